// Round 1
// baseline (1310.854 us; speedup 1.0000x reference)
//
#include <hip/hip_runtime.h>
#include <math.h>

#define S 2048
#define HID 1024
#define NH 16
#define HD 64
#define BH 32   // B * NH

// ---------------------------------------------------------------------------
// QKV projection: Y = X @ W^T + b, written to (b,h,s,d) layout.
// X: (4096, 1024) row-major. W: (1024, 1024) row-major (out, in).
// grid (16, 64, 3): x = n-tile (== head), y = m-tile, z = which of {q,k,v}
// ---------------------------------------------------------------------------
__global__ __launch_bounds__(256)
void qkv_proj(const float* __restrict__ X,
              const float* __restrict__ Wq, const float* __restrict__ bq_,
              const float* __restrict__ Wk, const float* __restrict__ bk_,
              const float* __restrict__ Wv, const float* __restrict__ bv_,
              float* __restrict__ Q, float* __restrict__ Kp, float* __restrict__ Vp)
{
    const int z = blockIdx.z;
    const float* __restrict__ W    = (z == 0) ? Wq : (z == 1 ? Wk : Wv);
    const float* __restrict__ bias = (z == 0) ? bq_ : (z == 1 ? bk_ : bv_);
    float* __restrict__ O          = (z == 0) ? Q : (z == 1 ? Kp : Vp);

    __shared__ float As[32][68];   // [k][m]
    __shared__ float Bs[32][68];   // [k][n]
    const int t  = threadIdx.x;
    const int tx = t & 15, ty = t >> 4;
    const int m0 = blockIdx.y * 64;
    const int n0 = blockIdx.x * 64;

    float acc[4][4] = {};
    for (int k0 = 0; k0 < HID; k0 += 32) {
#pragma unroll
        for (int p = 0; p < 2; ++p) {
            int l = t * 4 + p * 1024;
            int r = l >> 5, c = l & 31;
            float4 a = *(const float4*)(X + (size_t)(m0 + r) * HID + k0 + c);
            As[c + 0][r] = a.x; As[c + 1][r] = a.y; As[c + 2][r] = a.z; As[c + 3][r] = a.w;
            float4 w = *(const float4*)(W + (size_t)(n0 + r) * HID + k0 + c);
            Bs[c + 0][r] = w.x; Bs[c + 1][r] = w.y; Bs[c + 2][r] = w.z; Bs[c + 3][r] = w.w;
        }
        __syncthreads();
#pragma unroll
        for (int k = 0; k < 32; ++k) {
            float4 a4 = *(const float4*)&As[k][ty * 4];
            float4 b4 = *(const float4*)&Bs[k][tx * 4];
            float a[4] = {a4.x, a4.y, a4.z, a4.w};
            float b[4] = {b4.x, b4.y, b4.z, b4.w};
#pragma unroll
            for (int i = 0; i < 4; ++i)
#pragma unroll
                for (int j = 0; j < 4; ++j)
                    acc[i][j] = fmaf(a[i], b[j], acc[i][j]);
        }
        __syncthreads();
    }
    const int h = n0 >> 6;   // == blockIdx.x
#pragma unroll
    for (int i = 0; i < 4; ++i) {
        int m = m0 + ty * 4 + i;
        int b = m >> 11, s = m & 2047;
        float* orow = O + ((size_t)(b * NH + h) * S + s) * HD;
        float4 v;
        v.x = acc[i][0] + bias[n0 + tx * 4 + 0];
        v.y = acc[i][1] + bias[n0 + tx * 4 + 1];
        v.z = acc[i][2] + bias[n0 + tx * 4 + 2];
        v.w = acc[i][3] + bias[n0 + tx * 4 + 3];
        *(float4*)(orow + tx * 4) = v;
    }
}

// ---------------------------------------------------------------------------
// Scores: attn[bh,q,k] = 0.125 * dot(Q[bh,q,:], K[bh,k,:])
//                        + struct_emb[clip(dist[b,q,k],0,50)][h]
//                        + rw * (idf[b,q] + idf[b,k]);  mask==0 -> -inf
// grid (32, 32, 32): x = k-tile, y = q-tile, z = bh
// ---------------------------------------------------------------------------
__global__ __launch_bounds__(256)
void scores_kernel(const float* __restrict__ Q, const float* __restrict__ Kp,
                   const int* __restrict__ dist, const float* __restrict__ idf,
                   const int* __restrict__ amask, const float* __restrict__ semb,
                   const float* __restrict__ rw, float* __restrict__ attn)
{
    __shared__ float Qs[64][68];   // [d][q]
    __shared__ float Ks[64][68];   // [d][k]
    __shared__ float Se[51 * NH];
    const int t  = threadIdx.x;
    const int tx = t & 15, ty = t >> 4;
    const int k0 = blockIdx.x * 64;
    const int q0 = blockIdx.y * 64;
    const int bh = blockIdx.z;
    const int b  = bh >> 4, h = bh & 15;

    for (int p = t; p < 51 * NH; p += 256) Se[p] = semb[p];
#pragma unroll
    for (int p = 0; p < 4; ++p) {
        int l = t * 4 + p * 1024;
        int r = l >> 6, c = l & 63;
        float4 a = *(const float4*)(Q + ((size_t)bh * S + q0 + r) * HD + c);
        Qs[c + 0][r] = a.x; Qs[c + 1][r] = a.y; Qs[c + 2][r] = a.z; Qs[c + 3][r] = a.w;
        float4 kk = *(const float4*)(Kp + ((size_t)bh * S + k0 + r) * HD + c);
        Ks[c + 0][r] = kk.x; Ks[c + 1][r] = kk.y; Ks[c + 2][r] = kk.z; Ks[c + 3][r] = kk.w;
    }
    __syncthreads();

    float acc[4][4] = {};
#pragma unroll 16
    for (int d = 0; d < 64; ++d) {
        float4 a4 = *(const float4*)&Qs[d][ty * 4];
        float4 b4 = *(const float4*)&Ks[d][tx * 4];
        float a[4] = {a4.x, a4.y, a4.z, a4.w};
        float bb[4] = {b4.x, b4.y, b4.z, b4.w};
#pragma unroll
        for (int i = 0; i < 4; ++i)
#pragma unroll
            for (int j = 0; j < 4; ++j)
                acc[i][j] = fmaf(a[i], bb[j], acc[i][j]);
    }

    const float rwv = rw[0];
    const float scale = 0.125f;   // 1/sqrt(64)
    float idk[4]; int mk[4];
#pragma unroll
    for (int j = 0; j < 4; ++j) {
        idk[j] = idf[b * S + k0 + tx * 4 + j];
        mk[j]  = amask[b * S + k0 + tx * 4 + j];
    }
#pragma unroll
    for (int i = 0; i < 4; ++i) {
        int q = q0 + ty * 4 + i;
        float idq = idf[b * S + q];
        int4 dv = *(const int4*)(dist + ((size_t)b * S + q) * S + k0 + tx * 4);
        int dd[4] = {dv.x, dv.y, dv.z, dv.w};
        float4 outv;
        float* ov = &outv.x;
#pragma unroll
        for (int j = 0; j < 4; ++j) {
            int dc = dd[j];
            dc = dc < 0 ? 0 : (dc > 50 ? 50 : dc);
            float scv = acc[i][j] * scale + Se[dc * NH + h] + rwv * (idq + idk[j]);
            if (mk[j] == 0) scv = -INFINITY;
            ov[j] = scv;
        }
        *(float4*)(attn + ((size_t)bh * S + q) * S + k0 + tx * 4) = outv;
    }
}

// ---------------------------------------------------------------------------
// Row softmax in place. One block per row of 2048. 256 thr * 8 elems.
// ---------------------------------------------------------------------------
__global__ __launch_bounds__(256)
void softmax_kernel(float* __restrict__ attn)
{
    const size_t row = blockIdx.x;
    float* p = attn + row * (size_t)S;
    const int t = threadIdx.x;
    float4 v0 = *(const float4*)(p + t * 8);
    float4 v1 = *(const float4*)(p + t * 8 + 4);
    float vals[8] = {v0.x, v0.y, v0.z, v0.w, v1.x, v1.y, v1.z, v1.w};

    float m = vals[0];
#pragma unroll
    for (int i = 1; i < 8; ++i) m = fmaxf(m, vals[i]);
#pragma unroll
    for (int off = 32; off > 0; off >>= 1) m = fmaxf(m, __shfl_xor(m, off));
    __shared__ float rmax[4];
    __shared__ float rsum[4];
    if ((t & 63) == 0) rmax[t >> 6] = m;
    __syncthreads();
    m = fmaxf(fmaxf(rmax[0], rmax[1]), fmaxf(rmax[2], rmax[3]));

    float ssum = 0.f;
#pragma unroll
    for (int i = 0; i < 8; ++i) { vals[i] = __expf(vals[i] - m); ssum += vals[i]; }
#pragma unroll
    for (int off = 32; off > 0; off >>= 1) ssum += __shfl_xor(ssum, off);
    if ((t & 63) == 0) rsum[t >> 6] = ssum;
    __syncthreads();
    ssum = rsum[0] + rsum[1] + rsum[2] + rsum[3];
    float inv = 1.0f / ssum;

    v0 = make_float4(vals[0] * inv, vals[1] * inv, vals[2] * inv, vals[3] * inv);
    v1 = make_float4(vals[4] * inv, vals[5] * inv, vals[6] * inv, vals[7] * inv);
    *(float4*)(p + t * 8)     = v0;
    *(float4*)(p + t * 8 + 4) = v1;
}

// ---------------------------------------------------------------------------
// PV: OH[(b*S+q)*HID + h*HD + d] = sum_k attn[bh,q,k] * V[bh,k,d]
// grid (32, 32): x = q-tile, y = bh
// ---------------------------------------------------------------------------
__global__ __launch_bounds__(256)
void pv_kernel(const float* __restrict__ attn, const float* __restrict__ Vp,
               float* __restrict__ OH)
{
    __shared__ float As[32][68];   // [k][q]
    __shared__ float Vs[32][68];   // [k][d]
    const int t  = threadIdx.x;
    const int tx = t & 15, ty = t >> 4;
    const int q0 = blockIdx.x * 64;
    const int bh = blockIdx.y;
    const int b  = bh >> 4, h = bh & 15;

    float acc[4][4] = {};
    for (int k0 = 0; k0 < S; k0 += 32) {
#pragma unroll
        for (int p = 0; p < 2; ++p) {
            int l = t * 4 + p * 1024;
            {   // attn tile: 64 q x 32 k
                int r = l >> 5, c = l & 31;
                float4 a = *(const float4*)(attn + ((size_t)bh * S + q0 + r) * S + k0 + c);
                As[c + 0][r] = a.x; As[c + 1][r] = a.y; As[c + 2][r] = a.z; As[c + 3][r] = a.w;
            }
            {   // V tile: 32 k x 64 d (kept row-major)
                int r = l >> 6, c = l & 63;
                float4 v = *(const float4*)(Vp + ((size_t)bh * S + k0 + r) * HD + c);
                *(float4*)&Vs[r][c] = v;
            }
        }
        __syncthreads();
#pragma unroll
        for (int k = 0; k < 32; ++k) {
            float4 a4 = *(const float4*)&As[k][ty * 4];
            float4 b4 = *(const float4*)&Vs[k][tx * 4];
            float a[4] = {a4.x, a4.y, a4.z, a4.w};
            float bb[4] = {b4.x, b4.y, b4.z, b4.w};
#pragma unroll
            for (int i = 0; i < 4; ++i)
#pragma unroll
                for (int j = 0; j < 4; ++j)
                    acc[i][j] = fmaf(a[i], bb[j], acc[i][j]);
        }
        __syncthreads();
    }
#pragma unroll
    for (int i = 0; i < 4; ++i) {
        int q = q0 + ty * 4 + i;
        float4 v = make_float4(acc[i][0], acc[i][1], acc[i][2], acc[i][3]);
        *(float4*)(OH + ((size_t)b * S + q) * HID + h * HD + tx * 4) = v;
    }
}

// ---------------------------------------------------------------------------
// Output projection: out = OH @ Wo^T + bo, row-major (4096, 1024)
// grid (16, 64)
// ---------------------------------------------------------------------------
__global__ __launch_bounds__(256)
void out_proj(const float* __restrict__ X, const float* __restrict__ Wo,
              const float* __restrict__ bo_, float* __restrict__ Y)
{
    __shared__ float As[32][68];
    __shared__ float Bs[32][68];
    const int t  = threadIdx.x;
    const int tx = t & 15, ty = t >> 4;
    const int m0 = blockIdx.y * 64;
    const int n0 = blockIdx.x * 64;

    float acc[4][4] = {};
    for (int k0 = 0; k0 < HID; k0 += 32) {
#pragma unroll
        for (int p = 0; p < 2; ++p) {
            int l = t * 4 + p * 1024;
            int r = l >> 5, c = l & 31;
            float4 a = *(const float4*)(X + (size_t)(m0 + r) * HID + k0 + c);
            As[c + 0][r] = a.x; As[c + 1][r] = a.y; As[c + 2][r] = a.z; As[c + 3][r] = a.w;
            float4 w = *(const float4*)(Wo + (size_t)(n0 + r) * HID + k0 + c);
            Bs[c + 0][r] = w.x; Bs[c + 1][r] = w.y; Bs[c + 2][r] = w.z; Bs[c + 3][r] = w.w;
        }
        __syncthreads();
#pragma unroll
        for (int k = 0; k < 32; ++k) {
            float4 a4 = *(const float4*)&As[k][ty * 4];
            float4 b4 = *(const float4*)&Bs[k][tx * 4];
            float a[4] = {a4.x, a4.y, a4.z, a4.w};
            float b[4] = {b4.x, b4.y, b4.z, b4.w};
#pragma unroll
            for (int i = 0; i < 4; ++i)
#pragma unroll
                for (int j = 0; j < 4; ++j)
                    acc[i][j] = fmaf(a[i], b[j], acc[i][j]);
        }
        __syncthreads();
    }
#pragma unroll
    for (int i = 0; i < 4; ++i) {
        int m = m0 + ty * 4 + i;
        float4 v;
        v.x = acc[i][0] + bo_[n0 + tx * 4 + 0];
        v.y = acc[i][1] + bo_[n0 + tx * 4 + 1];
        v.z = acc[i][2] + bo_[n0 + tx * 4 + 2];
        v.w = acc[i][3] + bo_[n0 + tx * 4 + 3];
        *(float4*)(Y + (size_t)m * HID + n0 + tx * 4) = v;
    }
}

// ---------------------------------------------------------------------------
extern "C" void kernel_launch(void* const* d_in, const int* in_sizes, int n_in,
                              void* d_out, int out_size, void* d_ws, size_t ws_size,
                              hipStream_t stream)
{
    const float* hs   = (const float*)d_in[0];
    const int*   dist = (const int*)d_in[1];
    const float* idf  = (const float*)d_in[2];
    const int*   am   = (const int*)d_in[3];
    const float* Wq   = (const float*)d_in[4];
    const float* bq   = (const float*)d_in[5];
    const float* Wk   = (const float*)d_in[6];
    const float* bk   = (const float*)d_in[7];
    const float* Wv   = (const float*)d_in[8];
    const float* bv   = (const float*)d_in[9];
    const float* Wo   = (const float*)d_in[10];
    const float* bo   = (const float*)d_in[11];
    const float* se   = (const float*)d_in[12];
    const float* rw   = (const float*)d_in[13];

    float* out  = (float*)d_out;
    float* attn = out + (size_t)2 * S * HID;          // out is 2*2048*1024

    float* Q  = (float*)d_ws;                         // 4 buffers x 16 MB
    float* K  = Q + (size_t)BH * S * HD;
    float* V  = K + (size_t)BH * S * HD;
    float* OH = V + (size_t)BH * S * HD;

    dim3 blk(256);
    qkv_proj<<<dim3(16, 64, 3), blk, 0, stream>>>(hs, Wq, bq, Wk, bk, Wv, bv, Q, K, V);
    scores_kernel<<<dim3(32, 32, 32), blk, 0, stream>>>(Q, K, dist, idf, am, se, rw, attn);
    softmax_kernel<<<dim3(65536), blk, 0, stream>>>(attn);
    pv_kernel<<<dim3(32, 32), blk, 0, stream>>>(attn, V, OH);
    out_proj<<<dim3(16, 64), blk, 0, stream>>>(OH, Wo, bo, out);
}

// Round 2
// 1251.963 us; speedup vs baseline: 1.0470x; 1.0470x over previous
//
#include <hip/hip_runtime.h>
#include <math.h>

#define S 2048
#define HID 1024
#define NH 16
#define HD 64
#define BH 32   // B * NH

// ---------------------------------------------------------------------------
// QKV projection: Y = X @ W^T + b, written to (b,h,s,d) layout.
// ---------------------------------------------------------------------------
__global__ __launch_bounds__(256)
void qkv_proj(const float* __restrict__ X,
              const float* __restrict__ Wq, const float* __restrict__ bq_,
              const float* __restrict__ Wk, const float* __restrict__ bk_,
              const float* __restrict__ Wv, const float* __restrict__ bv_,
              float* __restrict__ Q, float* __restrict__ Kp, float* __restrict__ Vp)
{
    const int z = blockIdx.z;
    const float* __restrict__ W    = (z == 0) ? Wq : (z == 1 ? Wk : Wv);
    const float* __restrict__ bias = (z == 0) ? bq_ : (z == 1 ? bk_ : bv_);
    float* __restrict__ O          = (z == 0) ? Q : (z == 1 ? Kp : Vp);

    __shared__ float As[32][68];   // [k][m]
    __shared__ float Bs[32][68];   // [k][n]
    const int t  = threadIdx.x;
    const int tx = t & 15, ty = t >> 4;
    const int m0 = blockIdx.y * 64;
    const int n0 = blockIdx.x * 64;

    float acc[4][4] = {};
    for (int k0 = 0; k0 < HID; k0 += 32) {
#pragma unroll
        for (int p = 0; p < 2; ++p) {
            int l = t * 4 + p * 1024;
            int r = l >> 5, c = l & 31;
            float4 a = *(const float4*)(X + (size_t)(m0 + r) * HID + k0 + c);
            As[c + 0][r] = a.x; As[c + 1][r] = a.y; As[c + 2][r] = a.z; As[c + 3][r] = a.w;
            float4 w = *(const float4*)(W + (size_t)(n0 + r) * HID + k0 + c);
            Bs[c + 0][r] = w.x; Bs[c + 1][r] = w.y; Bs[c + 2][r] = w.z; Bs[c + 3][r] = w.w;
        }
        __syncthreads();
#pragma unroll
        for (int k = 0; k < 32; ++k) {
            float4 a4 = *(const float4*)&As[k][ty * 4];
            float4 b4 = *(const float4*)&Bs[k][tx * 4];
            float a[4] = {a4.x, a4.y, a4.z, a4.w};
            float b[4] = {b4.x, b4.y, b4.z, b4.w};
#pragma unroll
            for (int i = 0; i < 4; ++i)
#pragma unroll
                for (int j = 0; j < 4; ++j)
                    acc[i][j] = fmaf(a[i], b[j], acc[i][j]);
        }
        __syncthreads();
    }
    const int h = n0 >> 6;
#pragma unroll
    for (int i = 0; i < 4; ++i) {
        int m = m0 + ty * 4 + i;
        int b = m >> 11, s = m & 2047;
        float* orow = O + ((size_t)(b * NH + h) * S + s) * HD;
        float4 v;
        v.x = acc[i][0] + bias[n0 + tx * 4 + 0];
        v.y = acc[i][1] + bias[n0 + tx * 4 + 1];
        v.z = acc[i][2] + bias[n0 + tx * 4 + 2];
        v.w = acc[i][3] + bias[n0 + tx * 4 + 3];
        *(float4*)(orow + tx * 4) = v;
    }
}

// ---------------------------------------------------------------------------
// Scores + partial softmax stats.
// attn[bh,q,k] = raw biased score (written to d_out attn region)
// partials[(bh*S+q)*32 + kt] = (tile_max, tile_sumexp) for the 64-wide k-tile
// grid (32, 32, 32): x = k-tile, y = q-tile, z = bh
// ---------------------------------------------------------------------------
__global__ __launch_bounds__(256)
void scores_kernel(const float* __restrict__ Q, const float* __restrict__ Kp,
                   const int* __restrict__ dist, const float* __restrict__ idf,
                   const int* __restrict__ amask, const float* __restrict__ semb,
                   const float* __restrict__ rw, float* __restrict__ attn,
                   float2* __restrict__ partials)
{
    __shared__ float Qs[64][68];   // [d][q]
    __shared__ float Ks[64][68];   // [d][k]
    __shared__ float SeH[51];      // struct_emb column for this head
    const int t  = threadIdx.x;
    const int tx = t & 15, ty = t >> 4;
    const int k0 = blockIdx.x * 64;
    const int q0 = blockIdx.y * 64;
    const int bh = blockIdx.z;
    const int b  = bh >> 4, h = bh & 15;

    if (t < 51) SeH[t] = semb[t * NH + h];
#pragma unroll
    for (int p = 0; p < 4; ++p) {
        int l = t * 4 + p * 1024;
        int r = l >> 6, c = l & 63;
        float4 a = *(const float4*)(Q + ((size_t)bh * S + q0 + r) * HD + c);
        Qs[c + 0][r] = a.x; Qs[c + 1][r] = a.y; Qs[c + 2][r] = a.z; Qs[c + 3][r] = a.w;
        float4 kk = *(const float4*)(Kp + ((size_t)bh * S + k0 + r) * HD + c);
        Ks[c + 0][r] = kk.x; Ks[c + 1][r] = kk.y; Ks[c + 2][r] = kk.z; Ks[c + 3][r] = kk.w;
    }
    __syncthreads();

    float acc[4][4] = {};
#pragma unroll 16
    for (int d = 0; d < 64; ++d) {
        float4 a4 = *(const float4*)&Qs[d][ty * 4];
        float4 b4 = *(const float4*)&Ks[d][tx * 4];
        float a[4] = {a4.x, a4.y, a4.z, a4.w};
        float bb[4] = {b4.x, b4.y, b4.z, b4.w};
#pragma unroll
        for (int i = 0; i < 4; ++i)
#pragma unroll
            for (int j = 0; j < 4; ++j)
                acc[i][j] = fmaf(a[i], bb[j], acc[i][j]);
    }

    const float rwv = rw[0];
    const float scale = 0.125f;   // 1/sqrt(64)
    float idk[4]; int mk[4];
#pragma unroll
    for (int j = 0; j < 4; ++j) {
        idk[j] = idf[b * S + k0 + tx * 4 + j];
        mk[j]  = amask[b * S + k0 + tx * 4 + j];
    }
#pragma unroll
    for (int i = 0; i < 4; ++i) {
        int q = q0 + ty * 4 + i;
        float idq = idf[b * S + q];
        int4 dv = *(const int4*)(dist + ((size_t)b * S + q) * S + k0 + tx * 4);
        int dd[4] = {dv.x, dv.y, dv.z, dv.w};
        float4 outv;
        float* ov = &outv.x;
#pragma unroll
        for (int j = 0; j < 4; ++j) {
            int dc = dd[j];
            dc = dc < 0 ? 0 : (dc > 50 ? 50 : dc);
            float scv = acc[i][j] * scale + SeH[dc] + rwv * (idq + idk[j]);
            if (mk[j] == 0) scv = -INFINITY;
            ov[j] = scv;
        }
        *(float4*)(attn + ((size_t)bh * S + q) * S + k0 + tx * 4) = outv;

        // partial softmax stats for this 64-wide tile, reduced across tx lanes
        float m = fmaxf(fmaxf(ov[0], ov[1]), fmaxf(ov[2], ov[3]));
#pragma unroll
        for (int off = 1; off < 16; off <<= 1) m = fmaxf(m, __shfl_xor(m, off));
        float sum = 0.f;
        if (m > -INFINITY) {
#pragma unroll
            for (int j = 0; j < 4; ++j) sum += __expf(ov[j] - m);
        }
#pragma unroll
        for (int off = 1; off < 16; off <<= 1) sum += __shfl_xor(sum, off);
        if (tx == 0)
            partials[((size_t)bh * S + q) * 32 + blockIdx.x] = make_float2(m, sum);
    }
}

// ---------------------------------------------------------------------------
// Reduce 32 partials per row -> (row_max, 1/row_sum). One thread per row.
// ---------------------------------------------------------------------------
__global__ __launch_bounds__(256)
void reduce_rows(const float2* __restrict__ partials, float2* __restrict__ rowstats)
{
    const size_t row = (size_t)blockIdx.x * 256 + threadIdx.x;
    const float2* p = partials + row * 32;
    float M = -INFINITY;
#pragma unroll
    for (int j = 0; j < 32; ++j) M = fmaxf(M, p[j].x);
    float sum = 0.f;
#pragma unroll
    for (int j = 0; j < 32; ++j) {
        float2 v = p[j];
        if (v.x > -INFINITY) sum += v.y * __expf(v.x - M);
    }
    rowstats[row] = make_float2(M, 1.0f / sum);
}

// ---------------------------------------------------------------------------
// Fused normalize + attn write-back (in place) + PV.
// grid (32, 32): x = q-tile, y = bh
// ---------------------------------------------------------------------------
__global__ __launch_bounds__(256)
void pv_fused(float* __restrict__ attn, const float* __restrict__ Vp,
              const float2* __restrict__ rowstats, float* __restrict__ OH)
{
    __shared__ float Ps[64 * 33];  // [q][k], stride 33 (odd) -> conflict-free
    __shared__ float Vs[32][68];   // [k][d]
    const int t  = threadIdx.x;
    const int tx = t & 15, ty = t >> 4;
    const int q0 = blockIdx.x * 64;
    const int bh = blockIdx.y;
    const int b  = bh >> 4, h = bh & 15;

    // normalize rows handled by this thread during staging
    const int lr = t >> 3;            // 0..31
    const int lc = (t & 7) * 4;       // 0..28
    const float2 st0 = rowstats[(size_t)bh * S + q0 + lr];
    const float2 st1 = rowstats[(size_t)bh * S + q0 + lr + 32];

    float acc[4][4] = {};
    for (int k0 = 0; k0 < S; k0 += 32) {
#pragma unroll
        for (int p = 0; p < 2; ++p) {
            const int r = lr + p * 32;
            const float2 st = p ? st1 : st0;
            float* gp = attn + ((size_t)bh * S + q0 + r) * S + k0 + lc;
            float4 v = *(const float4*)gp;
            v.x = __expf(v.x - st.x) * st.y;
            v.y = __expf(v.y - st.x) * st.y;
            v.z = __expf(v.z - st.x) * st.y;
            v.w = __expf(v.w - st.x) * st.y;
            *(float4*)gp = v;                 // normalized attn out (in place)
            Ps[r * 33 + lc + 0] = v.x;
            Ps[r * 33 + lc + 1] = v.y;
            Ps[r * 33 + lc + 2] = v.z;
            Ps[r * 33 + lc + 3] = v.w;
        }
#pragma unroll
        for (int p = 0; p < 2; ++p) {
            int l = t * 4 + p * 1024;
            int r = l >> 6, c = l & 63;
            float4 v = *(const float4*)(Vp + ((size_t)bh * S + k0 + r) * HD + c);
            *(float4*)&Vs[r][c] = v;
        }
        __syncthreads();
#pragma unroll
        for (int k = 0; k < 32; ++k) {
            float a[4];
#pragma unroll
            for (int i = 0; i < 4; ++i) a[i] = Ps[(ty * 4 + i) * 33 + k];
            float4 b4 = *(const float4*)&Vs[k][tx * 4];
            float bb[4] = {b4.x, b4.y, b4.z, b4.w};
#pragma unroll
            for (int i = 0; i < 4; ++i)
#pragma unroll
                for (int j = 0; j < 4; ++j)
                    acc[i][j] = fmaf(a[i], bb[j], acc[i][j]);
        }
        __syncthreads();
    }
#pragma unroll
    for (int i = 0; i < 4; ++i) {
        int q = q0 + ty * 4 + i;
        float4 v = make_float4(acc[i][0], acc[i][1], acc[i][2], acc[i][3]);
        *(float4*)(OH + ((size_t)b * S + q) * HID + h * HD + tx * 4) = v;
    }
}

// ---------------------------------------------------------------------------
// Output projection: out = OH @ Wo^T + bo
// ---------------------------------------------------------------------------
__global__ __launch_bounds__(256)
void out_proj(const float* __restrict__ X, const float* __restrict__ Wo,
              const float* __restrict__ bo_, float* __restrict__ Y)
{
    __shared__ float As[32][68];
    __shared__ float Bs[32][68];
    const int t  = threadIdx.x;
    const int tx = t & 15, ty = t >> 4;
    const int m0 = blockIdx.y * 64;
    const int n0 = blockIdx.x * 64;

    float acc[4][4] = {};
    for (int k0 = 0; k0 < HID; k0 += 32) {
#pragma unroll
        for (int p = 0; p < 2; ++p) {
            int l = t * 4 + p * 1024;
            int r = l >> 5, c = l & 31;
            float4 a = *(const float4*)(X + (size_t)(m0 + r) * HID + k0 + c);
            As[c + 0][r] = a.x; As[c + 1][r] = a.y; As[c + 2][r] = a.z; As[c + 3][r] = a.w;
            float4 w = *(const float4*)(Wo + (size_t)(n0 + r) * HID + k0 + c);
            Bs[c + 0][r] = w.x; Bs[c + 1][r] = w.y; Bs[c + 2][r] = w.z; Bs[c + 3][r] = w.w;
        }
        __syncthreads();
#pragma unroll
        for (int k = 0; k < 32; ++k) {
            float4 a4 = *(const float4*)&As[k][ty * 4];
            float4 b4 = *(const float4*)&Bs[k][tx * 4];
            float a[4] = {a4.x, a4.y, a4.z, a4.w};
            float b[4] = {b4.x, b4.y, b4.z, b4.w};
#pragma unroll
            for (int i = 0; i < 4; ++i)
#pragma unroll
                for (int j = 0; j < 4; ++j)
                    acc[i][j] = fmaf(a[i], b[j], acc[i][j]);
        }
        __syncthreads();
    }
#pragma unroll
    for (int i = 0; i < 4; ++i) {
        int m = m0 + ty * 4 + i;
        float4 v;
        v.x = acc[i][0] + bo_[n0 + tx * 4 + 0];
        v.y = acc[i][1] + bo_[n0 + tx * 4 + 1];
        v.z = acc[i][2] + bo_[n0 + tx * 4 + 2];
        v.w = acc[i][3] + bo_[n0 + tx * 4 + 3];
        *(float4*)(Y + (size_t)m * HID + n0 + tx * 4) = v;
    }
}

// ---------------------------------------------------------------------------
extern "C" void kernel_launch(void* const* d_in, const int* in_sizes, int n_in,
                              void* d_out, int out_size, void* d_ws, size_t ws_size,
                              hipStream_t stream)
{
    const float* hs   = (const float*)d_in[0];
    const int*   dist = (const int*)d_in[1];
    const float* idf  = (const float*)d_in[2];
    const int*   am   = (const int*)d_in[3];
    const float* Wq   = (const float*)d_in[4];
    const float* bq   = (const float*)d_in[5];
    const float* Wk   = (const float*)d_in[6];
    const float* bk   = (const float*)d_in[7];
    const float* Wv   = (const float*)d_in[8];
    const float* bv   = (const float*)d_in[9];
    const float* Wo   = (const float*)d_in[10];
    const float* bo   = (const float*)d_in[11];
    const float* se   = (const float*)d_in[12];
    const float* rw   = (const float*)d_in[13];

    float* out  = (float*)d_out;
    float* attn = out + (size_t)2 * S * HID;          // 2*16*2048*2048 floats

    float*  Q        = (float*)d_ws;                  // 16 MB each
    float*  K        = Q + (size_t)BH * S * HD;
    float*  V        = K + (size_t)BH * S * HD;
    float*  OH       = V + (size_t)BH * S * HD;
    float2* partials = (float2*)(OH + (size_t)BH * S * HD);   // 16 MB
    float2* rowstats = partials + (size_t)BH * S * 32;        // 0.5 MB

    dim3 blk(256);
    qkv_proj<<<dim3(16, 64, 3), blk, 0, stream>>>(hs, Wq, bq, Wk, bk, Wv, bv, Q, K, V);
    scores_kernel<<<dim3(32, 32, 32), blk, 0, stream>>>(Q, K, dist, idf, am, se, rw,
                                                        attn, partials);
    reduce_rows<<<dim3(BH * S / 256), blk, 0, stream>>>(partials, rowstats);
    pv_fused<<<dim3(32, 32), blk, 0, stream>>>(attn, V, rowstats, OH);
    out_proj<<<dim3(16, 64), blk, 0, stream>>>(OH, Wo, bo, out);
}

// Round 3
// 1094.306 us; speedup vs baseline: 1.1979x; 1.1441x over previous
//
#include <hip/hip_runtime.h>
#include <math.h>

#define S 2048
#define HID 1024
#define NH 16
#define HD 64
#define BH 32   // B * NH

typedef __attribute__((ext_vector_type(8))) short bf16x8;
typedef __attribute__((ext_vector_type(4))) float f32x4;

__device__ __forceinline__ unsigned short f2bf(float f) {
    unsigned u = __float_as_uint(f);
    u += 0x7fffu + ((u >> 16) & 1u);
    return (unsigned short)(u >> 16);
}

// ---------------------------------------------------------------------------
// QKV projection: Y = X @ W^T + b. Q,K written as bf16 (b,h,s,d); V as fp32.
// grid (16, 64, 3): x = n-tile (== head), y = m-tile, z = which of {q,k,v}
// ---------------------------------------------------------------------------
__global__ __launch_bounds__(256)
void qkv_proj(const float* __restrict__ X,
              const float* __restrict__ Wq, const float* __restrict__ bq_,
              const float* __restrict__ Wk, const float* __restrict__ bk_,
              const float* __restrict__ Wv, const float* __restrict__ bv_,
              unsigned short* __restrict__ Qb, unsigned short* __restrict__ Kb,
              float* __restrict__ Vp)
{
    const int z = blockIdx.z;
    const float* __restrict__ W    = (z == 0) ? Wq : (z == 1 ? Wk : Wv);
    const float* __restrict__ bias = (z == 0) ? bq_ : (z == 1 ? bk_ : bv_);

    __shared__ float As[32][68];   // [k][m]
    __shared__ float Bs[32][68];   // [k][n]
    const int t  = threadIdx.x;
    const int tx = t & 15, ty = t >> 4;
    const int m0 = blockIdx.y * 64;
    const int n0 = blockIdx.x * 64;

    float acc[4][4] = {};
    for (int k0 = 0; k0 < HID; k0 += 32) {
#pragma unroll
        for (int p = 0; p < 2; ++p) {
            int l = t * 4 + p * 1024;
            int r = l >> 5, c = l & 31;
            float4 a = *(const float4*)(X + (size_t)(m0 + r) * HID + k0 + c);
            As[c + 0][r] = a.x; As[c + 1][r] = a.y; As[c + 2][r] = a.z; As[c + 3][r] = a.w;
            float4 w = *(const float4*)(W + (size_t)(n0 + r) * HID + k0 + c);
            Bs[c + 0][r] = w.x; Bs[c + 1][r] = w.y; Bs[c + 2][r] = w.z; Bs[c + 3][r] = w.w;
        }
        __syncthreads();
#pragma unroll
        for (int k = 0; k < 32; ++k) {
            float4 a4 = *(const float4*)&As[k][ty * 4];
            float4 b4 = *(const float4*)&Bs[k][tx * 4];
            float a[4] = {a4.x, a4.y, a4.z, a4.w};
            float b[4] = {b4.x, b4.y, b4.z, b4.w};
#pragma unroll
            for (int i = 0; i < 4; ++i)
#pragma unroll
                for (int j = 0; j < 4; ++j)
                    acc[i][j] = fmaf(a[i], b[j], acc[i][j]);
        }
        __syncthreads();
    }
    const int h = n0 >> 6;
#pragma unroll
    for (int i = 0; i < 4; ++i) {
        int m = m0 + ty * 4 + i;
        int b = m >> 11, s = m & 2047;
        float4 v;
        v.x = acc[i][0] + bias[n0 + tx * 4 + 0];
        v.y = acc[i][1] + bias[n0 + tx * 4 + 1];
        v.z = acc[i][2] + bias[n0 + tx * 4 + 2];
        v.w = acc[i][3] + bias[n0 + tx * 4 + 3];
        size_t off = ((size_t)(b * NH + h) * S + s) * HD + tx * 4;
        if (z == 2) {
            *(float4*)(Vp + off) = v;
        } else {
            unsigned short* ob = (z == 0 ? Qb : Kb) + off;
            ushort4 o;
            o.x = f2bf(v.x); o.y = f2bf(v.y); o.z = f2bf(v.z); o.w = f2bf(v.w);
            *(ushort4*)ob = o;
        }
    }
}

// ---------------------------------------------------------------------------
// Scores via MFMA + partial softmax stats.
// 1-D grid of 8192 blocks; work remapped so the 16 heads sharing one
// (b, q-tile, k-tile) dist tile keep the same n%8 -> same XCD -> L2 hits.
// Block: 256 thr = 4 waves (2x2), tile 128q x 128k, bf16 16x16x32 MFMA.
// ---------------------------------------------------------------------------
__global__ __launch_bounds__(256)
void scores_mfma(const unsigned short* __restrict__ Qb,
                 const unsigned short* __restrict__ Kb,
                 const int* __restrict__ dist, const float* __restrict__ idf,
                 const int* __restrict__ amask, const float* __restrict__ semb,
                 const float* __restrict__ rw, float* __restrict__ attn,
                 float2* __restrict__ partials)
{
    __shared__ unsigned short Qs[128 * 72];   // stride 72 ush = 144 B (2-way only)
    __shared__ unsigned short Ks[128 * 72];
    __shared__ float SeH[51];

    const int n   = blockIdx.x;
    const int xcd = n & 7;
    const int h   = (n >> 3) & 15;
    const int g   = (n >> 7) * 8 + xcd;       // 0..511
    const int kt  = g & 15;
    const int qt  = (g >> 4) & 15;
    const int b   = g >> 8;
    const int bh  = b * NH + h;
    const int q0  = qt * 128, k0 = kt * 128;

    const int t = threadIdx.x;
    if (t < 51) SeH[t] = semb[t * NH + h];

    {   // stage Q,K tiles: 2 threads/row, 64 B each
        const int row = t >> 1, half = t & 1;
        const uint4* qs = (const uint4*)(Qb + ((size_t)bh * S + q0 + row) * HD + half * 32);
        const uint4* ks = (const uint4*)(Kb + ((size_t)bh * S + k0 + row) * HD + half * 32);
        uint4* qd = (uint4*)&Qs[row * 72 + half * 32];
        uint4* kd = (uint4*)&Ks[row * 72 + half * 32];
#pragma unroll
        for (int i = 0; i < 4; ++i) { qd[i] = qs[i]; kd[i] = ks[i]; }
    }
    __syncthreads();

    const int lane = t & 63, w = t >> 6;
    const int wm = w >> 1, wn = w & 1;
    const int lr = lane & 15, lg = lane >> 4;

    bf16x8 qa[2][4], kf[2][4];
#pragma unroll
    for (int ks = 0; ks < 2; ++ks)
#pragma unroll
        for (int i = 0; i < 4; ++i) {
            qa[ks][i] = *(const bf16x8*)&Qs[(wm * 64 + i * 16 + lr) * 72 + ks * 32 + lg * 8];
            kf[ks][i] = *(const bf16x8*)&Ks[(wn * 64 + i * 16 + lr) * 72 + ks * 32 + lg * 8];
        }

    f32x4 acc[4][4] = {{{0.f,0.f,0.f,0.f}}};
#pragma unroll
    for (int mi = 0; mi < 4; ++mi)
#pragma unroll
        for (int ni = 0; ni < 4; ++ni) {
            f32x4 c = {0.f, 0.f, 0.f, 0.f};
            c = __builtin_amdgcn_mfma_f32_16x16x32_bf16(qa[0][mi], kf[0][ni], c, 0, 0, 0);
            c = __builtin_amdgcn_mfma_f32_16x16x32_bf16(qa[1][mi], kf[1][ni], c, 0, 0, 0);
            acc[mi][ni] = c;
        }

    // epilogue: bias + mask + write + per-(row, 64-k-tile) partial stats
    const float rwv = rw[0];
    const int kcb = k0 + wn * 64;
    float idk[4]; int mk[4];
#pragma unroll
    for (int ni = 0; ni < 4; ++ni) {
        int k = kcb + ni * 16 + lr;
        idk[ni] = idf[b * S + k];
        mk[ni]  = amask[b * S + k];
    }
#pragma unroll
    for (int mi = 0; mi < 4; ++mi)
#pragma unroll
        for (int r = 0; r < 4; ++r) {
            const int q = q0 + wm * 64 + mi * 16 + lg * 4 + r;
            const float idq = idf[b * S + q];
            const int* drow = dist + ((size_t)b * S + q) * S + kcb;
            float* arow = attn + ((size_t)bh * S + q) * S + kcb;
            float sc[4];
#pragma unroll
            for (int ni = 0; ni < 4; ++ni) {
                int dc = drow[ni * 16 + lr];
                dc = dc < 0 ? 0 : (dc > 50 ? 50 : dc);
                float v = acc[mi][ni][r] * 0.125f + SeH[dc] + rwv * (idq + idk[ni]);
                if (mk[ni] == 0) v = -INFINITY;
                sc[ni] = v;
                arow[ni * 16 + lr] = v;
            }
            float m = fmaxf(fmaxf(sc[0], sc[1]), fmaxf(sc[2], sc[3]));
#pragma unroll
            for (int off = 1; off < 16; off <<= 1) m = fmaxf(m, __shfl_xor(m, off));
            float ssum = 0.f;
            if (m > -INFINITY) {
#pragma unroll
                for (int ni = 0; ni < 4; ++ni) ssum += __expf(sc[ni] - m);
            }
#pragma unroll
            for (int off = 1; off < 16; off <<= 1) ssum += __shfl_xor(ssum, off);
            if (lr == 0)
                partials[((size_t)bh * S + q) * 32 + kt * 2 + wn] = make_float2(m, ssum);
        }
}

// ---------------------------------------------------------------------------
// Reduce 32 partials per row -> (row_max, 1/row_sum). One thread per row.
// ---------------------------------------------------------------------------
__global__ __launch_bounds__(256)
void reduce_rows(const float2* __restrict__ partials, float2* __restrict__ rowstats)
{
    const size_t row = (size_t)blockIdx.x * 256 + threadIdx.x;
    const float2* p = partials + row * 32;
    float M = -INFINITY;
#pragma unroll
    for (int j = 0; j < 32; ++j) M = fmaxf(M, p[j].x);
    float sum = 0.f;
#pragma unroll
    for (int j = 0; j < 32; ++j) {
        float2 v = p[j];
        if (v.x > -INFINITY) sum += v.y * __expf(v.x - M);
    }
    rowstats[row] = make_float2(M, 1.0f / sum);
}

// ---------------------------------------------------------------------------
// Fused normalize + attn write-back (in place) + PV.
// grid (32, 32): x = q-tile, y = bh
// ---------------------------------------------------------------------------
__global__ __launch_bounds__(256)
void pv_fused(float* __restrict__ attn, const float* __restrict__ Vp,
              const float2* __restrict__ rowstats, float* __restrict__ OH)
{
    __shared__ float Ps[64 * 33];  // [q][k], stride 33 -> conflict-free
    __shared__ float Vs[32][68];   // [k][d]
    const int t  = threadIdx.x;
    const int tx = t & 15, ty = t >> 4;
    const int q0 = blockIdx.x * 64;
    const int bh = blockIdx.y;
    const int b  = bh >> 4, h = bh & 15;

    const int lr = t >> 3;            // 0..31
    const int lc = (t & 7) * 4;       // 0..28
    const float2 st0 = rowstats[(size_t)bh * S + q0 + lr];
    const float2 st1 = rowstats[(size_t)bh * S + q0 + lr + 32];

    float acc[4][4] = {};
    for (int k0 = 0; k0 < S; k0 += 32) {
#pragma unroll
        for (int p = 0; p < 2; ++p) {
            const int r = lr + p * 32;
            const float2 st = p ? st1 : st0;
            float* gp = attn + ((size_t)bh * S + q0 + r) * S + k0 + lc;
            float4 v = *(const float4*)gp;
            v.x = __expf(v.x - st.x) * st.y;
            v.y = __expf(v.y - st.x) * st.y;
            v.z = __expf(v.z - st.x) * st.y;
            v.w = __expf(v.w - st.x) * st.y;
            *(float4*)gp = v;                 // normalized attn out (in place)
            Ps[r * 33 + lc + 0] = v.x;
            Ps[r * 33 + lc + 1] = v.y;
            Ps[r * 33 + lc + 2] = v.z;
            Ps[r * 33 + lc + 3] = v.w;
        }
#pragma unroll
        for (int p = 0; p < 2; ++p) {
            int l = t * 4 + p * 1024;
            int r = l >> 6, c = l & 63;
            float4 v = *(const float4*)(Vp + ((size_t)bh * S + k0 + r) * HD + c);
            *(float4*)&Vs[r][c] = v;
        }
        __syncthreads();
#pragma unroll
        for (int k = 0; k < 32; ++k) {
            float a[4];
#pragma unroll
            for (int i = 0; i < 4; ++i) a[i] = Ps[(ty * 4 + i) * 33 + k];
            float4 b4 = *(const float4*)&Vs[k][tx * 4];
            float bb[4] = {b4.x, b4.y, b4.z, b4.w};
#pragma unroll
            for (int i = 0; i < 4; ++i)
#pragma unroll
                for (int j = 0; j < 4; ++j)
                    acc[i][j] = fmaf(a[i], bb[j], acc[i][j]);
        }
        __syncthreads();
    }
#pragma unroll
    for (int i = 0; i < 4; ++i) {
        int q = q0 + ty * 4 + i;
        float4 v = make_float4(acc[i][0], acc[i][1], acc[i][2], acc[i][3]);
        *(float4*)(OH + ((size_t)b * S + q) * HID + h * HD + tx * 4) = v;
    }
}

// ---------------------------------------------------------------------------
// Output projection: out = OH @ Wo^T + bo
// ---------------------------------------------------------------------------
__global__ __launch_bounds__(256)
void out_proj(const float* __restrict__ X, const float* __restrict__ Wo,
              const float* __restrict__ bo_, float* __restrict__ Y)
{
    __shared__ float As[32][68];
    __shared__ float Bs[32][68];
    const int t  = threadIdx.x;
    const int tx = t & 15, ty = t >> 4;
    const int m0 = blockIdx.y * 64;
    const int n0 = blockIdx.x * 64;

    float acc[4][4] = {};
    for (int k0 = 0; k0 < HID; k0 += 32) {
#pragma unroll
        for (int p = 0; p < 2; ++p) {
            int l = t * 4 + p * 1024;
            int r = l >> 5, c = l & 31;
            float4 a = *(const float4*)(X + (size_t)(m0 + r) * HID + k0 + c);
            As[c + 0][r] = a.x; As[c + 1][r] = a.y; As[c + 2][r] = a.z; As[c + 3][r] = a.w;
            float4 w = *(const float4*)(Wo + (size_t)(n0 + r) * HID + k0 + c);
            Bs[c + 0][r] = w.x; Bs[c + 1][r] = w.y; Bs[c + 2][r] = w.z; Bs[c + 3][r] = w.w;
        }
        __syncthreads();
#pragma unroll
        for (int k = 0; k < 32; ++k) {
            float4 a4 = *(const float4*)&As[k][ty * 4];
            float4 b4 = *(const float4*)&Bs[k][tx * 4];
            float a[4] = {a4.x, a4.y, a4.z, a4.w};
            float b[4] = {b4.x, b4.y, b4.z, b4.w};
#pragma unroll
            for (int i = 0; i < 4; ++i)
#pragma unroll
                for (int j = 0; j < 4; ++j)
                    acc[i][j] = fmaf(a[i], b[j], acc[i][j]);
        }
        __syncthreads();
    }
#pragma unroll
    for (int i = 0; i < 4; ++i) {
        int m = m0 + ty * 4 + i;
        float4 v;
        v.x = acc[i][0] + bo_[n0 + tx * 4 + 0];
        v.y = acc[i][1] + bo_[n0 + tx * 4 + 1];
        v.z = acc[i][2] + bo_[n0 + tx * 4 + 2];
        v.w = acc[i][3] + bo_[n0 + tx * 4 + 3];
        *(float4*)(Y + (size_t)m * HID + n0 + tx * 4) = v;
    }
}

// ---------------------------------------------------------------------------
extern "C" void kernel_launch(void* const* d_in, const int* in_sizes, int n_in,
                              void* d_out, int out_size, void* d_ws, size_t ws_size,
                              hipStream_t stream)
{
    const float* hs   = (const float*)d_in[0];
    const int*   dist = (const int*)d_in[1];
    const float* idf  = (const float*)d_in[2];
    const int*   am   = (const int*)d_in[3];
    const float* Wq   = (const float*)d_in[4];
    const float* bq   = (const float*)d_in[5];
    const float* Wk   = (const float*)d_in[6];
    const float* bk   = (const float*)d_in[7];
    const float* Wv   = (const float*)d_in[8];
    const float* bv   = (const float*)d_in[9];
    const float* Wo   = (const float*)d_in[10];
    const float* bo   = (const float*)d_in[11];
    const float* se   = (const float*)d_in[12];
    const float* rw   = (const float*)d_in[13];

    float* out  = (float*)d_out;
    float* attn = out + (size_t)2 * S * HID;          // 2*16*2048*2048 floats

    unsigned short* Qb = (unsigned short*)d_ws;                 // 8 MB
    unsigned short* Kb = Qb + (size_t)BH * S * HD;              // 8 MB
    float*  V        = (float*)(Kb + (size_t)BH * S * HD);      // 16 MB
    float*  OH       = V + (size_t)BH * S * HD;                 // 16 MB
    float2* partials = (float2*)(OH + (size_t)BH * S * HD);     // 16 MB
    float2* rowstats = partials + (size_t)BH * S * 32;          // 0.5 MB

    dim3 blk(256);
    qkv_proj<<<dim3(16, 64, 3), blk, 0, stream>>>(hs, Wq, bq, Wk, bk, Wv, bv, Qb, Kb, V);
    scores_mfma<<<dim3(8192), blk, 0, stream>>>(Qb, Kb, dist, idf, am, se, rw,
                                                attn, partials);
    reduce_rows<<<dim3(BH * S / 256), blk, 0, stream>>>(partials, rowstats);
    pv_fused<<<dim3(32, 32), blk, 0, stream>>>(attn, V, rowstats, OH);
    out_proj<<<dim3(16, 64), blk, 0, stream>>>(OH, Wo, bo, out);
}

// Round 4
// 668.869 us; speedup vs baseline: 1.9598x; 1.6361x over previous
//
#include <hip/hip_runtime.h>
#include <math.h>

#define S 2048
#define HID 1024
#define NH 16
#define HD 64
#define BH 32   // B * NH

typedef __attribute__((ext_vector_type(8))) short bf16x8;
typedef __attribute__((ext_vector_type(4))) float f32x4;
typedef __attribute__((ext_vector_type(8))) unsigned short ush8;
typedef unsigned short u16;

__device__ __forceinline__ u16 f2bf(float f) {
    unsigned u = __float_as_uint(f);
    u += 0x7fffu + ((u >> 16) & 1u);
    return (u16)(u >> 16);
}
__device__ __forceinline__ float bf2f(u16 h) {
    return __uint_as_float(((unsigned)h) << 16);
}

// ---------------------------------------------------------------------------
// Split fp32 -> (hi, lo) bf16 pair, truncation both (x ~= hi + lo, err ~2^-16)
// ---------------------------------------------------------------------------
__global__ __launch_bounds__(256)
void split_prep(const float* __restrict__ s, u16* __restrict__ h,
                u16* __restrict__ l, int n4)
{
    int i = blockIdx.x * 256 + threadIdx.x;
    if (i >= n4) return;
    float4 v = ((const float4*)s)[i];
    ushort4 hv, lv;
#define SP(c, k) { unsigned u = __float_as_uint(v.c);                      \
                   unsigned hb = u & 0xffff0000u;                          \
                   float d = v.c - __uint_as_float(hb);                    \
                   hv.k = (u16)(u >> 16);                                  \
                   lv.k = (u16)(__float_as_uint(d) >> 16); }
    SP(x, x) SP(y, y) SP(z, z) SP(w, w)
#undef SP
    ((ushort4*)h)[i] = hv;
    ((ushort4*)l)[i] = lv;
}

// ---------------------------------------------------------------------------
// Split-precision MFMA GEMM: Y = X @ W^T + b, X,W given as (hi,lo) bf16.
// Tile 128x128, BK=32, 4 waves. Output bf16 to (b,h,s,d) layout (Q/K/V).
// grid (8, 32, 3)
// ---------------------------------------------------------------------------
__global__ __launch_bounds__(256)
void qkv_mfma(const u16* __restrict__ Xh, const u16* __restrict__ Xl,
              const u16* __restrict__ Wh_q, const u16* __restrict__ Wl_q,
              const u16* __restrict__ Wh_k, const u16* __restrict__ Wl_k,
              const u16* __restrict__ Wh_v, const u16* __restrict__ Wl_v,
              const float* __restrict__ bq_, const float* __restrict__ bk_,
              const float* __restrict__ bv_,
              u16* __restrict__ Qb, u16* __restrict__ Kb, u16* __restrict__ Vb)
{
    const int z = blockIdx.z;
    const u16* __restrict__ Wh = z == 0 ? Wh_q : (z == 1 ? Wh_k : Wh_v);
    const u16* __restrict__ Wl = z == 0 ? Wl_q : (z == 1 ? Wl_k : Wl_v);
    const float* __restrict__ bias = z == 0 ? bq_ : (z == 1 ? bk_ : bv_);
    u16* __restrict__ Ob = z == 0 ? Qb : (z == 1 ? Kb : Vb);

    __shared__ u16 Ah[128 * 40], Al[128 * 40], Bh[128 * 40], Bl[128 * 40];
    const int t = threadIdx.x;
    const int m0 = blockIdx.y * 128, n0 = blockIdx.x * 128;
    const int srow = t >> 1, scol = (t & 1) * 16;
    const int lane = t & 63, w = t >> 6, wm = w >> 1, wn = w & 1;
    const int lr = lane & 15, lg = lane >> 4;

    f32x4 acc[4][4] = {{{0.f, 0.f, 0.f, 0.f}}};
    for (int k0 = 0; k0 < HID; k0 += 32) {
        size_t ao = (size_t)(m0 + srow) * HID + k0 + scol;
        size_t bo = (size_t)(n0 + srow) * HID + k0 + scol;
        ush8 a0 = *(const ush8*)(Xh + ao), a1 = *(const ush8*)(Xh + ao + 8);
        ush8 a2 = *(const ush8*)(Xl + ao), a3 = *(const ush8*)(Xl + ao + 8);
        ush8 b0 = *(const ush8*)(Wh + bo), b1 = *(const ush8*)(Wh + bo + 8);
        ush8 b2 = *(const ush8*)(Wl + bo), b3 = *(const ush8*)(Wl + bo + 8);
        __syncthreads();
        *(ush8*)&Ah[srow * 40 + scol] = a0; *(ush8*)&Ah[srow * 40 + scol + 8] = a1;
        *(ush8*)&Al[srow * 40 + scol] = a2; *(ush8*)&Al[srow * 40 + scol + 8] = a3;
        *(ush8*)&Bh[srow * 40 + scol] = b0; *(ush8*)&Bh[srow * 40 + scol + 8] = b1;
        *(ush8*)&Bl[srow * 40 + scol] = b2; *(ush8*)&Bl[srow * 40 + scol + 8] = b3;
        __syncthreads();
        bf16x8 fbh[4], fbl[4];
#pragma unroll
        for (int ni = 0; ni < 4; ++ni) {
            fbh[ni] = *(const bf16x8*)&Bh[(wn * 64 + ni * 16 + lr) * 40 + lg * 8];
            fbl[ni] = *(const bf16x8*)&Bl[(wn * 64 + ni * 16 + lr) * 40 + lg * 8];
        }
#pragma unroll
        for (int mi = 0; mi < 4; ++mi) {
            bf16x8 fah = *(const bf16x8*)&Ah[(wm * 64 + mi * 16 + lr) * 40 + lg * 8];
            bf16x8 fal = *(const bf16x8*)&Al[(wm * 64 + mi * 16 + lr) * 40 + lg * 8];
#pragma unroll
            for (int ni = 0; ni < 4; ++ni) {
                f32x4 c = acc[mi][ni];
                c = __builtin_amdgcn_mfma_f32_16x16x32_bf16(fah, fbh[ni], c, 0, 0, 0);
                c = __builtin_amdgcn_mfma_f32_16x16x32_bf16(fah, fbl[ni], c, 0, 0, 0);
                c = __builtin_amdgcn_mfma_f32_16x16x32_bf16(fal, fbh[ni], c, 0, 0, 0);
                acc[mi][ni] = c;
            }
        }
    }
    const int hh = blockIdx.x * 2 + wn;
    float bv4[4];
#pragma unroll
    for (int ni = 0; ni < 4; ++ni) bv4[ni] = bias[n0 + wn * 64 + ni * 16 + lr];
#pragma unroll
    for (int mi = 0; mi < 4; ++mi)
#pragma unroll
        for (int r = 0; r < 4; ++r) {
            int m = m0 + wm * 64 + mi * 16 + lg * 4 + r;
            int b = m >> 11, s = m & 2047;
#pragma unroll
            for (int ni = 0; ni < 4; ++ni) {
                float v = acc[mi][ni][r] + bv4[ni];
                Ob[((size_t)(b * NH + hh) * S + s) * HD + ni * 16 + lr] = f2bf(v);
            }
        }
}

// ---------------------------------------------------------------------------
// out = OH @ Wo^T + bo (split precision, fp32 out). grid (8, 32)
// ---------------------------------------------------------------------------
__global__ __launch_bounds__(256)
void out_mfma(const u16* __restrict__ Xh, const u16* __restrict__ Xl,
              const u16* __restrict__ Wh, const u16* __restrict__ Wl,
              const float* __restrict__ bo_, float* __restrict__ Y)
{
    __shared__ u16 Ah[128 * 40], Al[128 * 40], Bh[128 * 40], Bl[128 * 40];
    const int t = threadIdx.x;
    const int m0 = blockIdx.y * 128, n0 = blockIdx.x * 128;
    const int srow = t >> 1, scol = (t & 1) * 16;
    const int lane = t & 63, w = t >> 6, wm = w >> 1, wn = w & 1;
    const int lr = lane & 15, lg = lane >> 4;

    f32x4 acc[4][4] = {{{0.f, 0.f, 0.f, 0.f}}};
    for (int k0 = 0; k0 < HID; k0 += 32) {
        size_t ao = (size_t)(m0 + srow) * HID + k0 + scol;
        size_t bo = (size_t)(n0 + srow) * HID + k0 + scol;
        ush8 a0 = *(const ush8*)(Xh + ao), a1 = *(const ush8*)(Xh + ao + 8);
        ush8 a2 = *(const ush8*)(Xl + ao), a3 = *(const ush8*)(Xl + ao + 8);
        ush8 b0 = *(const ush8*)(Wh + bo), b1 = *(const ush8*)(Wh + bo + 8);
        ush8 b2 = *(const ush8*)(Wl + bo), b3 = *(const ush8*)(Wl + bo + 8);
        __syncthreads();
        *(ush8*)&Ah[srow * 40 + scol] = a0; *(ush8*)&Ah[srow * 40 + scol + 8] = a1;
        *(ush8*)&Al[srow * 40 + scol] = a2; *(ush8*)&Al[srow * 40 + scol + 8] = a3;
        *(ush8*)&Bh[srow * 40 + scol] = b0; *(ush8*)&Bh[srow * 40 + scol + 8] = b1;
        *(ush8*)&Bl[srow * 40 + scol] = b2; *(ush8*)&Bl[srow * 40 + scol + 8] = b3;
        __syncthreads();
        bf16x8 fbh[4], fbl[4];
#pragma unroll
        for (int ni = 0; ni < 4; ++ni) {
            fbh[ni] = *(const bf16x8*)&Bh[(wn * 64 + ni * 16 + lr) * 40 + lg * 8];
            fbl[ni] = *(const bf16x8*)&Bl[(wn * 64 + ni * 16 + lr) * 40 + lg * 8];
        }
#pragma unroll
        for (int mi = 0; mi < 4; ++mi) {
            bf16x8 fah = *(const bf16x8*)&Ah[(wm * 64 + mi * 16 + lr) * 40 + lg * 8];
            bf16x8 fal = *(const bf16x8*)&Al[(wm * 64 + mi * 16 + lr) * 40 + lg * 8];
#pragma unroll
            for (int ni = 0; ni < 4; ++ni) {
                f32x4 c = acc[mi][ni];
                c = __builtin_amdgcn_mfma_f32_16x16x32_bf16(fah, fbh[ni], c, 0, 0, 0);
                c = __builtin_amdgcn_mfma_f32_16x16x32_bf16(fah, fbl[ni], c, 0, 0, 0);
                c = __builtin_amdgcn_mfma_f32_16x16x32_bf16(fal, fbh[ni], c, 0, 0, 0);
                acc[mi][ni] = c;
            }
        }
    }
    float bv4[4];
#pragma unroll
    for (int ni = 0; ni < 4; ++ni) bv4[ni] = bo_[n0 + wn * 64 + ni * 16 + lr];
#pragma unroll
    for (int mi = 0; mi < 4; ++mi)
#pragma unroll
        for (int r = 0; r < 4; ++r) {
            int m = m0 + wm * 64 + mi * 16 + lg * 4 + r;
#pragma unroll
            for (int ni = 0; ni < 4; ++ni)
                Y[(size_t)m * HID + n0 + wn * 64 + ni * 16 + lr] =
                    acc[mi][ni][r] + bv4[ni];
        }
}

// ---------------------------------------------------------------------------
// Pass 1: scores via MFMA -> partial softmax stats ONLY (no score write).
// grid 8192 (XCD-swizzled), tile 128q x 128k.
// ---------------------------------------------------------------------------
__global__ __launch_bounds__(256)
void stats_mfma(const u16* __restrict__ Qb, const u16* __restrict__ Kb,
                const int* __restrict__ dist, const float* __restrict__ idf,
                const int* __restrict__ amask, const float* __restrict__ semb,
                const float* __restrict__ rw, float2* __restrict__ partials)
{
    __shared__ u16 Qs[128 * 72];
    __shared__ u16 Ks[128 * 72];
    __shared__ float SeH[51];

    const int n   = blockIdx.x;
    const int xcd = n & 7;
    const int h   = (n >> 3) & 15;
    const int g   = (n >> 7) * 8 + xcd;
    const int kt  = g & 15;
    const int qt  = (g >> 4) & 15;
    const int b   = g >> 8;
    const int bh  = b * NH + h;
    const int q0  = qt * 128, k0 = kt * 128;

    const int t = threadIdx.x;
    if (t < 51) SeH[t] = semb[t * NH + h];

    {
        const int row = t >> 1, half = t & 1;
        const uint4* qs = (const uint4*)(Qb + ((size_t)bh * S + q0 + row) * HD + half * 32);
        const uint4* ks = (const uint4*)(Kb + ((size_t)bh * S + k0 + row) * HD + half * 32);
        uint4* qd = (uint4*)&Qs[row * 72 + half * 32];
        uint4* kd = (uint4*)&Ks[row * 72 + half * 32];
#pragma unroll
        for (int i = 0; i < 4; ++i) { qd[i] = qs[i]; kd[i] = ks[i]; }
    }
    __syncthreads();

    const int lane = t & 63, w = t >> 6;
    const int wm = w >> 1, wn = w & 1;
    const int lr = lane & 15, lg = lane >> 4;

    bf16x8 qa[2][4], kf[2][4];
#pragma unroll
    for (int ks = 0; ks < 2; ++ks)
#pragma unroll
        for (int i = 0; i < 4; ++i) {
            qa[ks][i] = *(const bf16x8*)&Qs[(wm * 64 + i * 16 + lr) * 72 + ks * 32 + lg * 8];
            kf[ks][i] = *(const bf16x8*)&Ks[(wn * 64 + i * 16 + lr) * 72 + ks * 32 + lg * 8];
        }

    f32x4 acc[4][4];
#pragma unroll
    for (int mi = 0; mi < 4; ++mi)
#pragma unroll
        for (int ni = 0; ni < 4; ++ni) {
            f32x4 c = {0.f, 0.f, 0.f, 0.f};
            c = __builtin_amdgcn_mfma_f32_16x16x32_bf16(qa[0][mi], kf[0][ni], c, 0, 0, 0);
            c = __builtin_amdgcn_mfma_f32_16x16x32_bf16(qa[1][mi], kf[1][ni], c, 0, 0, 0);
            acc[mi][ni] = c;
        }

    const float rwv = rw[0];
    const int kcb = k0 + wn * 64;
    float idk[4]; int mk[4];
#pragma unroll
    for (int ni = 0; ni < 4; ++ni) {
        int k = kcb + ni * 16 + lr;
        idk[ni] = idf[b * S + k];
        mk[ni]  = amask[b * S + k];
    }
#pragma unroll
    for (int mi = 0; mi < 4; ++mi)
#pragma unroll
        for (int r = 0; r < 4; ++r) {
            const int q = q0 + wm * 64 + mi * 16 + lg * 4 + r;
            const float idq = idf[b * S + q];
            const int* drow = dist + ((size_t)b * S + q) * S + kcb;
            float sc[4];
#pragma unroll
            for (int ni = 0; ni < 4; ++ni) {
                int dc = drow[ni * 16 + lr];
                dc = dc < 0 ? 0 : (dc > 50 ? 50 : dc);
                float v = acc[mi][ni][r] * 0.125f + SeH[dc] + rwv * (idq + idk[ni]);
                if (mk[ni] == 0) v = -INFINITY;
                sc[ni] = v;
            }
            float m = fmaxf(fmaxf(sc[0], sc[1]), fmaxf(sc[2], sc[3]));
#pragma unroll
            for (int off = 1; off < 16; off <<= 1) m = fmaxf(m, __shfl_xor(m, off));
            float ssum = 0.f;
            if (m > -INFINITY) {
#pragma unroll
                for (int ni = 0; ni < 4; ++ni) ssum += __expf(sc[ni] - m);
            }
#pragma unroll
            for (int off = 1; off < 16; off <<= 1) ssum += __shfl_xor(ssum, off);
            if (lr == 0)
                partials[((size_t)bh * S + q) * 32 + kt * 2 + wn] = make_float2(m, ssum);
        }
}

// ---------------------------------------------------------------------------
// Reduce 32 partials per row -> (row_max, 1/row_sum).
// ---------------------------------------------------------------------------
__global__ __launch_bounds__(256)
void reduce_rows(const float2* __restrict__ partials, float2* __restrict__ rowstats)
{
    const size_t row = (size_t)blockIdx.x * 256 + threadIdx.x;
    const float2* p = partials + row * 32;
    float M = -INFINITY;
#pragma unroll
    for (int j = 0; j < 32; ++j) M = fmaxf(M, p[j].x);
    float sum = 0.f;
#pragma unroll
    for (int j = 0; j < 32; ++j) {
        float2 v = p[j];
        if (v.x > -INFINITY) sum += v.y * __expf(v.x - M);
    }
    rowstats[row] = make_float2(M, 1.0f / sum);
}

// ---------------------------------------------------------------------------
// Pass 2: recompute scores (MFMA, bitwise-identical fragments), normalize,
// write fp32 attn ONCE, and accumulate PV via MFMA (bf16 P through LDS).
// grid 1024: swizzled so the 16 heads of one (b, q-tile) share an XCD.
// Block = 4 waves; wave w owns q rows [w*16, w*16+16).
// ---------------------------------------------------------------------------
__global__ __launch_bounds__(256)
void attn_pv(const u16* __restrict__ Qb, const u16* __restrict__ Kb,
             const u16* __restrict__ Vb,
             const int* __restrict__ dist, const float* __restrict__ idf,
             const int* __restrict__ amask, const float* __restrict__ semb,
             const float* __restrict__ rw, const float2* __restrict__ rowstats,
             float* __restrict__ attn, u16* __restrict__ OHh, u16* __restrict__ OHl)
{
    __shared__ u16 Qs[64 * 72], Ks[64 * 72], Ps[64 * 72], Vts[64 * 72];
    __shared__ float SeH[51];
    __shared__ float2 Rst[64];

    const int n = blockIdx.x;
    const int xcd = n & 7, ii = n >> 3;
    const int h = ii >> 3, pair = xcd * 8 + (ii & 7);
    const int b = pair >> 5, qt = pair & 31;
    const int bh = b * NH + h, q0 = qt * 64;

    const int t = threadIdx.x, lane = t & 63, w = t >> 6;
    const int lr = lane & 15, lg = lane >> 4;

    if (t < 51) SeH[t] = semb[t * NH + h];
    if (t < 64) Rst[t] = rowstats[(size_t)bh * S + q0 + t];
    {
        int r = t >> 2, c = (t & 3) * 16;
        *(ush8*)&Qs[r * 72 + c]     = *(const ush8*)(Qb + ((size_t)bh * S + q0 + r) * HD + c);
        *(ush8*)&Qs[r * 72 + c + 8] = *(const ush8*)(Qb + ((size_t)bh * S + q0 + r) * HD + c + 8);
    }
    __syncthreads();

    bf16x8 qa[2];
    qa[0] = *(const bf16x8*)&Qs[(w * 16 + lr) * 72 + lg * 8];
    qa[1] = *(const bf16x8*)&Qs[(w * 16 + lr) * 72 + 32 + lg * 8];

    const float rwv = rw[0];
    float Mv[4], Iv[4], idqv[4];
#pragma unroll
    for (int r = 0; r < 4; ++r) {
        float2 st = Rst[w * 16 + lg * 4 + r];
        Mv[r] = st.x; Iv[r] = st.y;
        idqv[r] = idf[b * S + q0 + w * 16 + lg * 4 + r];
    }

    f32x4 oacc[4] = {{0.f, 0.f, 0.f, 0.f}};

    for (int k0 = 0; k0 < S; k0 += 64) {
        {   // stage K chunk (row-major) + V chunk (transposed)
            int r = t >> 2, c = (t & 3) * 16;
            *(ush8*)&Ks[r * 72 + c]     = *(const ush8*)(Kb + ((size_t)bh * S + k0 + r) * HD + c);
            *(ush8*)&Ks[r * 72 + c + 8] = *(const ush8*)(Kb + ((size_t)bh * S + k0 + r) * HD + c + 8);
            int kr = t & 63, dseg = t >> 6;
            ush8 v0 = *(const ush8*)(Vb + ((size_t)bh * S + k0 + kr) * HD + dseg * 16);
            ush8 v1 = *(const ush8*)(Vb + ((size_t)bh * S + k0 + kr) * HD + dseg * 16 + 8);
#pragma unroll
            for (int j = 0; j < 8; ++j) {
                Vts[(dseg * 16 + j) * 72 + kr]     = v0[j];
                Vts[(dseg * 16 + 8 + j) * 72 + kr] = v1[j];
            }
        }
        __syncthreads();

        // QK^T for this 64-k chunk
        f32x4 c4[4];
#pragma unroll
        for (int ni = 0; ni < 4; ++ni) {
            bf16x8 kf0 = *(const bf16x8*)&Ks[(ni * 16 + lr) * 72 + lg * 8];
            bf16x8 kf1 = *(const bf16x8*)&Ks[(ni * 16 + lr) * 72 + 32 + lg * 8];
            f32x4 c = {0.f, 0.f, 0.f, 0.f};
            c = __builtin_amdgcn_mfma_f32_16x16x32_bf16(qa[0], kf0, c, 0, 0, 0);
            c = __builtin_amdgcn_mfma_f32_16x16x32_bf16(qa[1], kf1, c, 0, 0, 0);
            c4[ni] = c;
        }

        // epilogue: bias -> p -> attn write + bf16 P into LDS
        float idk[4]; int mk[4];
#pragma unroll
        for (int ni = 0; ni < 4; ++ni) {
            int k = k0 + ni * 16 + lr;
            idk[ni] = idf[b * S + k];
            mk[ni]  = amask[b * S + k];
        }
#pragma unroll
        for (int r = 0; r < 4; ++r) {
            const int q = q0 + w * 16 + lg * 4 + r;
            const int* drow = dist + ((size_t)b * S + q) * S + k0;
            float* arow = attn + ((size_t)bh * S + q) * S + k0;
#pragma unroll
            for (int ni = 0; ni < 4; ++ni) {
                int dc = drow[ni * 16 + lr];
                dc = dc < 0 ? 0 : (dc > 50 ? 50 : dc);
                float sv = c4[ni][r] * 0.125f + SeH[dc] + rwv * (idqv[r] + idk[ni]);
                if (mk[ni] == 0) sv = -INFINITY;
                float p = __expf(sv - Mv[r]) * Iv[r];
                arow[ni * 16 + lr] = p;
                Ps[(w * 16 + lg * 4 + r) * 72 + ni * 16 + lr] = f2bf(p);
            }
        }
        __syncthreads();

        // PV accumulate
        bf16x8 pa0 = *(const bf16x8*)&Ps[(w * 16 + lr) * 72 + lg * 8];
        bf16x8 pa1 = *(const bf16x8*)&Ps[(w * 16 + lr) * 72 + 32 + lg * 8];
#pragma unroll
        for (int ni = 0; ni < 4; ++ni) {
            bf16x8 vb0 = *(const bf16x8*)&Vts[(ni * 16 + lr) * 72 + lg * 8];
            bf16x8 vb1 = *(const bf16x8*)&Vts[(ni * 16 + lr) * 72 + 32 + lg * 8];
            oacc[ni] = __builtin_amdgcn_mfma_f32_16x16x32_bf16(pa0, vb0, oacc[ni], 0, 0, 0);
            oacc[ni] = __builtin_amdgcn_mfma_f32_16x16x32_bf16(pa1, vb1, oacc[ni], 0, 0, 0);
        }
        __syncthreads();
    }

    // OH epilogue: split hi/lo bf16 for the out-projection GEMM
#pragma unroll
    for (int r = 0; r < 4; ++r) {
        const int q = q0 + w * 16 + lg * 4 + r;
#pragma unroll
        for (int ni = 0; ni < 4; ++ni) {
            float v = oacc[ni][r];
            u16 hi = f2bf(v);
            u16 lo = f2bf(v - bf2f(hi));
            size_t off = ((size_t)b * S + q) * HID + h * HD + ni * 16 + lr;
            OHh[off] = hi;
            OHl[off] = lo;
        }
    }
}

// ---------------------------------------------------------------------------
extern "C" void kernel_launch(void* const* d_in, const int* in_sizes, int n_in,
                              void* d_out, int out_size, void* d_ws, size_t ws_size,
                              hipStream_t stream)
{
    const float* hs   = (const float*)d_in[0];
    const int*   dist = (const int*)d_in[1];
    const float* idf  = (const float*)d_in[2];
    const int*   am   = (const int*)d_in[3];
    const float* Wq   = (const float*)d_in[4];
    const float* bq   = (const float*)d_in[5];
    const float* Wk   = (const float*)d_in[6];
    const float* bk   = (const float*)d_in[7];
    const float* Wv   = (const float*)d_in[8];
    const float* bv   = (const float*)d_in[9];
    const float* Wo   = (const float*)d_in[10];
    const float* bo   = (const float*)d_in[11];
    const float* se   = (const float*)d_in[12];
    const float* rw   = (const float*)d_in[13];

    float* out  = (float*)d_out;
    float* attn = out + (size_t)2 * S * HID;

    // X hi/lo hide in the (not yet written) attn output region
    u16* Xh = (u16*)attn;
    u16* Xl = Xh + (size_t)4096 * 1024;

    // workspace layout (60.5 MB)
    u16* Qb  = (u16*)d_ws;
    u16* Kb  = Qb  + (size_t)BH * S * HD;
    u16* Vb  = Kb  + (size_t)BH * S * HD;
    u16* OHh = Vb  + (size_t)BH * S * HD;
    u16* OHl = OHh + (size_t)4096 * 1024;
    u16* Woh = OHl + (size_t)4096 * 1024;
    u16* Wol = Woh + (size_t)1024 * 1024;
    float2* partials = (float2*)(Wol + (size_t)1024 * 1024);
    float2* rowstats = partials + (size_t)BH * S * 32;
    // Wq/k/v hi/lo alias the partials region (dead before stats_mfma writes it)
    u16* Wqh = (u16*)partials;
    u16* Wql = Wqh + (size_t)1024 * 1024;
    u16* Wkh = Wql + (size_t)1024 * 1024;
    u16* Wkl = Wkh + (size_t)1024 * 1024;
    u16* Wvh = Wkl + (size_t)1024 * 1024;
    u16* Wvl = Wvh + (size_t)1024 * 1024;

    dim3 blk(256);
    split_prep<<<dim3(4096), blk, 0, stream>>>(hs, Xh, Xl, 4096 * 1024 / 4);
    split_prep<<<dim3(1024), blk, 0, stream>>>(Wq, Wqh, Wql, 1024 * 1024 / 4);
    split_prep<<<dim3(1024), blk, 0, stream>>>(Wk, Wkh, Wkl, 1024 * 1024 / 4);
    split_prep<<<dim3(1024), blk, 0, stream>>>(Wv, Wvh, Wvl, 1024 * 1024 / 4);
    split_prep<<<dim3(1024), blk, 0, stream>>>(Wo, Woh, Wol, 1024 * 1024 / 4);

    qkv_mfma<<<dim3(8, 32, 3), blk, 0, stream>>>(Xh, Xl, Wqh, Wql, Wkh, Wkl,
                                                 Wvh, Wvl, bq, bk, bv, Qb, Kb, Vb);
    stats_mfma<<<dim3(8192), blk, 0, stream>>>(Qb, Kb, dist, idf, am, se, rw, partials);
    reduce_rows<<<dim3(BH * S / 256), blk, 0, stream>>>(partials, rowstats);
    attn_pv<<<dim3(1024), blk, 0, stream>>>(Qb, Kb, Vb, dist, idf, am, se, rw,
                                            rowstats, attn, OHh, OHl);
    out_mfma<<<dim3(8, 32), blk, 0, stream>>>(OHh, OHl, Woh, Wol, bo, out);
}

// Round 5
// 486.407 us; speedup vs baseline: 2.6950x; 1.3751x over previous
//
#include <hip/hip_runtime.h>
#include <math.h>

#define S 2048
#define HID 1024
#define NH 16
#define HD 64
#define BH 32   // B * NH

typedef __attribute__((ext_vector_type(8))) short bf16x8;
typedef __attribute__((ext_vector_type(4))) float f32x4;
typedef __attribute__((ext_vector_type(8))) unsigned short ush8;
typedef unsigned short u16;

__device__ __forceinline__ u16 f2bf(float f) {
    unsigned u = __float_as_uint(f);
    u += 0x7fffu + ((u >> 16) & 1u);
    return (u16)(u >> 16);
}
__device__ __forceinline__ float bf2f(u16 h) {
    return __uint_as_float(((unsigned)h) << 16);
}

// ---------------------------------------------------------------------------
// Split fp32 -> (hi, lo) bf16 for X and all four weights in ONE launch.
// grid 8192 x 256: float4 index i; [0,1M) = X, then 4 x 256K for Wq/Wk/Wv/Wo.
// ---------------------------------------------------------------------------
__global__ __launch_bounds__(256)
void split_all(const float* __restrict__ X,  const float* __restrict__ Wq,
               const float* __restrict__ Wk, const float* __restrict__ Wv,
               const float* __restrict__ Wo,
               u16* __restrict__ Xh,  u16* __restrict__ Xl,
               u16* __restrict__ Wqh, u16* __restrict__ Wql,
               u16* __restrict__ Wkh, u16* __restrict__ Wkl,
               u16* __restrict__ Wvh, u16* __restrict__ Wvl,
               u16* __restrict__ Woh, u16* __restrict__ Wol)
{
    size_t i = (size_t)blockIdx.x * 256 + threadIdx.x;
    const float* s; u16* h; u16* l; size_t o;
    if (i < (size_t)(1u << 20)) { s = X; h = Xh; l = Xl; o = i; }
    else {
        size_t j = i - (1u << 20);
        int wsel = (int)(j >> 18); o = j & ((1u << 18) - 1);
        s = wsel == 0 ? Wq  : wsel == 1 ? Wk  : wsel == 2 ? Wv  : Wo;
        h = wsel == 0 ? Wqh : wsel == 1 ? Wkh : wsel == 2 ? Wvh : Woh;
        l = wsel == 0 ? Wql : wsel == 1 ? Wkl : wsel == 2 ? Wvl : Wol;
    }
    float4 v = ((const float4*)s)[o];
    ushort4 hv, lv;
#define SP(c, k) { unsigned u = __float_as_uint(v.c);                      \
                   unsigned hb = u & 0xffff0000u;                          \
                   float d = v.c - __uint_as_float(hb);                    \
                   hv.k = (u16)(u >> 16);                                  \
                   lv.k = (u16)(__float_as_uint(d) >> 16); }
    SP(x, x) SP(y, y) SP(z, z) SP(w, w)
#undef SP
    ((ushort4*)h)[o] = hv;
    ((ushort4*)l)[o] = lv;
}

// ---------------------------------------------------------------------------
// Split-precision MFMA GEMM: Y = X @ W^T + b, X,W given as (hi,lo) bf16.
// Tile 128x128, BK=32, 4 waves. Output bf16 to (b,h,s,d) layout (Q/K/V).
// grid (8, 32, 3)
// ---------------------------------------------------------------------------
__global__ __launch_bounds__(256)
void qkv_mfma(const u16* __restrict__ Xh, const u16* __restrict__ Xl,
              const u16* __restrict__ Wh_q, const u16* __restrict__ Wl_q,
              const u16* __restrict__ Wh_k, const u16* __restrict__ Wl_k,
              const u16* __restrict__ Wh_v, const u16* __restrict__ Wl_v,
              const float* __restrict__ bq_, const float* __restrict__ bk_,
              const float* __restrict__ bv_,
              u16* __restrict__ Qb, u16* __restrict__ Kb, u16* __restrict__ Vb)
{
    const int z = blockIdx.z;
    const u16* __restrict__ Wh = z == 0 ? Wh_q : (z == 1 ? Wh_k : Wh_v);
    const u16* __restrict__ Wl = z == 0 ? Wl_q : (z == 1 ? Wl_k : Wl_v);
    const float* __restrict__ bias = z == 0 ? bq_ : (z == 1 ? bk_ : bv_);
    u16* __restrict__ Ob = z == 0 ? Qb : (z == 1 ? Kb : Vb);

    __shared__ u16 Ah[128 * 40], Al[128 * 40], Bh[128 * 40], Bl[128 * 40];
    const int t = threadIdx.x;
    const int m0 = blockIdx.y * 128, n0 = blockIdx.x * 128;
    const int srow = t >> 1, scol = (t & 1) * 16;
    const int lane = t & 63, w = t >> 6, wm = w >> 1, wn = w & 1;
    const int lr = lane & 15, lg = lane >> 4;

    f32x4 acc[4][4] = {{{0.f, 0.f, 0.f, 0.f}}};
    for (int k0 = 0; k0 < HID; k0 += 32) {
        size_t ao = (size_t)(m0 + srow) * HID + k0 + scol;
        size_t bo = (size_t)(n0 + srow) * HID + k0 + scol;
        ush8 a0 = *(const ush8*)(Xh + ao), a1 = *(const ush8*)(Xh + ao + 8);
        ush8 a2 = *(const ush8*)(Xl + ao), a3 = *(const ush8*)(Xl + ao + 8);
        ush8 b0 = *(const ush8*)(Wh + bo), b1 = *(const ush8*)(Wh + bo + 8);
        ush8 b2 = *(const ush8*)(Wl + bo), b3 = *(const ush8*)(Wl + bo + 8);
        __syncthreads();
        *(ush8*)&Ah[srow * 40 + scol] = a0; *(ush8*)&Ah[srow * 40 + scol + 8] = a1;
        *(ush8*)&Al[srow * 40 + scol] = a2; *(ush8*)&Al[srow * 40 + scol + 8] = a3;
        *(ush8*)&Bh[srow * 40 + scol] = b0; *(ush8*)&Bh[srow * 40 + scol + 8] = b1;
        *(ush8*)&Bl[srow * 40 + scol] = b2; *(ush8*)&Bl[srow * 40 + scol + 8] = b3;
        __syncthreads();
        bf16x8 fbh[4], fbl[4];
#pragma unroll
        for (int ni = 0; ni < 4; ++ni) {
            fbh[ni] = *(const bf16x8*)&Bh[(wn * 64 + ni * 16 + lr) * 40 + lg * 8];
            fbl[ni] = *(const bf16x8*)&Bl[(wn * 64 + ni * 16 + lr) * 40 + lg * 8];
        }
#pragma unroll
        for (int mi = 0; mi < 4; ++mi) {
            bf16x8 fah = *(const bf16x8*)&Ah[(wm * 64 + mi * 16 + lr) * 40 + lg * 8];
            bf16x8 fal = *(const bf16x8*)&Al[(wm * 64 + mi * 16 + lr) * 40 + lg * 8];
#pragma unroll
            for (int ni = 0; ni < 4; ++ni) {
                f32x4 c = acc[mi][ni];
                c = __builtin_amdgcn_mfma_f32_16x16x32_bf16(fah, fbh[ni], c, 0, 0, 0);
                c = __builtin_amdgcn_mfma_f32_16x16x32_bf16(fah, fbl[ni], c, 0, 0, 0);
                c = __builtin_amdgcn_mfma_f32_16x16x32_bf16(fal, fbh[ni], c, 0, 0, 0);
                acc[mi][ni] = c;
            }
        }
    }
    const int hh = blockIdx.x * 2 + wn;
    float bv4[4];
#pragma unroll
    for (int ni = 0; ni < 4; ++ni) bv4[ni] = bias[n0 + wn * 64 + ni * 16 + lr];
#pragma unroll
    for (int mi = 0; mi < 4; ++mi)
#pragma unroll
        for (int r = 0; r < 4; ++r) {
            int m = m0 + wm * 64 + mi * 16 + lg * 4 + r;
            int b = m >> 11, s = m & 2047;
#pragma unroll
            for (int ni = 0; ni < 4; ++ni) {
                float v = acc[mi][ni][r] + bv4[ni];
                Ob[((size_t)(b * NH + hh) * S + s) * HD + ni * 16 + lr] = f2bf(v);
            }
        }
}

// ---------------------------------------------------------------------------
// out = OH @ Wo^T + bo (split precision, fp32 out). grid (8, 32)
// ---------------------------------------------------------------------------
__global__ __launch_bounds__(256)
void out_mfma(const u16* __restrict__ Xh, const u16* __restrict__ Xl,
              const u16* __restrict__ Wh, const u16* __restrict__ Wl,
              const float* __restrict__ bo_, float* __restrict__ Y)
{
    __shared__ u16 Ah[128 * 40], Al[128 * 40], Bh[128 * 40], Bl[128 * 40];
    const int t = threadIdx.x;
    const int m0 = blockIdx.y * 128, n0 = blockIdx.x * 128;
    const int srow = t >> 1, scol = (t & 1) * 16;
    const int lane = t & 63, w = t >> 6, wm = w >> 1, wn = w & 1;
    const int lr = lane & 15, lg = lane >> 4;

    f32x4 acc[4][4] = {{{0.f, 0.f, 0.f, 0.f}}};
    for (int k0 = 0; k0 < HID; k0 += 32) {
        size_t ao = (size_t)(m0 + srow) * HID + k0 + scol;
        size_t bo = (size_t)(n0 + srow) * HID + k0 + scol;
        ush8 a0 = *(const ush8*)(Xh + ao), a1 = *(const ush8*)(Xh + ao + 8);
        ush8 a2 = *(const ush8*)(Xl + ao), a3 = *(const ush8*)(Xl + ao + 8);
        ush8 b0 = *(const ush8*)(Wh + bo), b1 = *(const ush8*)(Wh + bo + 8);
        ush8 b2 = *(const ush8*)(Wl + bo), b3 = *(const ush8*)(Wl + bo + 8);
        __syncthreads();
        *(ush8*)&Ah[srow * 40 + scol] = a0; *(ush8*)&Ah[srow * 40 + scol + 8] = a1;
        *(ush8*)&Al[srow * 40 + scol] = a2; *(ush8*)&Al[srow * 40 + scol + 8] = a3;
        *(ush8*)&Bh[srow * 40 + scol] = b0; *(ush8*)&Bh[srow * 40 + scol + 8] = b1;
        *(ush8*)&Bl[srow * 40 + scol] = b2; *(ush8*)&Bl[srow * 40 + scol + 8] = b3;
        __syncthreads();
        bf16x8 fbh[4], fbl[4];
#pragma unroll
        for (int ni = 0; ni < 4; ++ni) {
            fbh[ni] = *(const bf16x8*)&Bh[(wn * 64 + ni * 16 + lr) * 40 + lg * 8];
            fbl[ni] = *(const bf16x8*)&Bl[(wn * 64 + ni * 16 + lr) * 40 + lg * 8];
        }
#pragma unroll
        for (int mi = 0; mi < 4; ++mi) {
            bf16x8 fah = *(const bf16x8*)&Ah[(wm * 64 + mi * 16 + lr) * 40 + lg * 8];
            bf16x8 fal = *(const bf16x8*)&Al[(wm * 64 + mi * 16 + lr) * 40 + lg * 8];
#pragma unroll
            for (int ni = 0; ni < 4; ++ni) {
                f32x4 c = acc[mi][ni];
                c = __builtin_amdgcn_mfma_f32_16x16x32_bf16(fah, fbh[ni], c, 0, 0, 0);
                c = __builtin_amdgcn_mfma_f32_16x16x32_bf16(fah, fbl[ni], c, 0, 0, 0);
                c = __builtin_amdgcn_mfma_f32_16x16x32_bf16(fal, fbh[ni], c, 0, 0, 0);
                acc[mi][ni] = c;
            }
        }
    }
    float bv4[4];
#pragma unroll
    for (int ni = 0; ni < 4; ++ni) bv4[ni] = bo_[n0 + wn * 64 + ni * 16 + lr];
#pragma unroll
    for (int mi = 0; mi < 4; ++mi)
#pragma unroll
        for (int r = 0; r < 4; ++r) {
            int m = m0 + wm * 64 + mi * 16 + lg * 4 + r;
#pragma unroll
            for (int ni = 0; ni < 4; ++ni)
                Y[(size_t)m * HID + n0 + wn * 64 + ni * 16 + lr] =
                    acc[mi][ni][r] + bv4[ni];
        }
}

// ---------------------------------------------------------------------------
// Fused attention: pass A computes row softmax stats online (no HBM partials),
// pass B recomputes scores (bitwise-identical fragments), writes normalized
// attn once, and accumulates PV. 8 waves x 128 q-rows per block, KVBLK=64,
// 2 barriers/chunk; P is wave-local in LDS (no barrier between write & read).
// grid 512: xcd swizzle keeps all 16 heads of one (b,qt) on one XCD.
// ---------------------------------------------------------------------------
__global__ __launch_bounds__(512)
void attn_pv(const u16* __restrict__ Qb, const u16* __restrict__ Kb,
             const u16* __restrict__ Vb,
             const int* __restrict__ dist, const float* __restrict__ idf,
             const int* __restrict__ amask, const float* __restrict__ semb,
             const float* __restrict__ rw,
             float* __restrict__ attn, u16* __restrict__ OHh, u16* __restrict__ OHl)
{
    __shared__ u16 QPs[128 * 72];   // Q fragments, then reused as P
    __shared__ u16 Ks[64 * 72];
    __shared__ u16 Vts[64 * 72];    // transposed V: [d][k]
    __shared__ float SeH[51];

    const int n = blockIdx.x;
    const int xcd = n & 7, rest = n >> 3;       // rest 0..63
    const int h = rest & 15;
    const int pair = xcd * 4 + (rest >> 4);     // 0..31; same for all 16 h
    const int b = pair >> 4, qt = pair & 15;
    const int bh = b * NH + h, q0 = qt * 128;

    const int t = threadIdx.x, lane = t & 63, w = t >> 6;
    const int lr = lane & 15, lg = lane >> 4;

    if (t < 51) SeH[t] = semb[t * NH + h];
    {   // stage 128x64 Q tile
        int r = t >> 2, c = (t & 3) * 16;
        const u16* qrow = Qb + ((size_t)bh * S + q0 + r) * HD + c;
        *(ush8*)&QPs[r * 72 + c]     = *(const ush8*)qrow;
        *(ush8*)&QPs[r * 72 + c + 8] = *(const ush8*)(qrow + 8);
    }
    __syncthreads();

    bf16x8 qa0 = *(const bf16x8*)&QPs[(w * 16 + lr) * 72 + lg * 8];
    bf16x8 qa1 = *(const bf16x8*)&QPs[(w * 16 + lr) * 72 + 32 + lg * 8];

    const float rwv = rw[0];
    float idqv[4];
#pragma unroll
    for (int r = 0; r < 4; ++r)
        idqv[r] = idf[b * S + q0 + w * 16 + lg * 4 + r];

    // ---------------- pass A: online row stats ----------------
    float M[4]    = {-INFINITY, -INFINITY, -INFINITY, -INFINITY};
    float Ssum[4] = {0.f, 0.f, 0.f, 0.f};

    for (int k0 = 0; k0 < S; k0 += 64) {
        __syncthreads();   // previous chunk's Ks readers done
        *(ush8*)&Ks[(t >> 3) * 72 + (t & 7) * 8] =
            *(const ush8*)(Kb + ((size_t)bh * S + k0 + (t >> 3)) * HD + (t & 7) * 8);
        __syncthreads();

        f32x4 c4[4];
#pragma unroll
        for (int ni = 0; ni < 4; ++ni) {
            bf16x8 kf0 = *(const bf16x8*)&Ks[(ni * 16 + lr) * 72 + lg * 8];
            bf16x8 kf1 = *(const bf16x8*)&Ks[(ni * 16 + lr) * 72 + 32 + lg * 8];
            f32x4 c = {0.f, 0.f, 0.f, 0.f};
            c = __builtin_amdgcn_mfma_f32_16x16x32_bf16(qa0, kf0, c, 0, 0, 0);
            c = __builtin_amdgcn_mfma_f32_16x16x32_bf16(qa1, kf1, c, 0, 0, 0);
            c4[ni] = c;
        }

        float idk[4]; int mk[4];
#pragma unroll
        for (int ni = 0; ni < 4; ++ni) {
            int k = k0 + ni * 16 + lr;
            idk[ni] = idf[b * S + k];
            mk[ni]  = amask[b * S + k];
        }
#pragma unroll
        for (int r = 0; r < 4; ++r) {
            const int q = q0 + w * 16 + lg * 4 + r;
            const int* drow = dist + ((size_t)b * S + q) * S + k0;
            float sc[4];
#pragma unroll
            for (int ni = 0; ni < 4; ++ni) {
                int dc = drow[ni * 16 + lr];
                dc = dc < 0 ? 0 : (dc > 50 ? 50 : dc);
                float v = c4[ni][r] * 0.125f + SeH[dc] + rwv * (idqv[r] + idk[ni]);
                if (mk[ni] == 0) v = -INFINITY;
                sc[ni] = v;
            }
            float m = fmaxf(fmaxf(sc[0], sc[1]), fmaxf(sc[2], sc[3]));
#pragma unroll
            for (int off = 1; off < 16; off <<= 1) m = fmaxf(m, __shfl_xor(m, off));
            if (m > -INFINITY) {
                float s = 0.f;
#pragma unroll
                for (int ni = 0; ni < 4; ++ni) s += __expf(sc[ni] - m);
#pragma unroll
                for (int off = 1; off < 16; off <<= 1) s += __shfl_xor(s, off);
                if (m > M[r]) {
                    Ssum[r] = Ssum[r] * __expf(M[r] - m) + s;
                    M[r] = m;
                } else {
                    Ssum[r] += s * __expf(m - M[r]);
                }
            }
        }
    }
    float Iv[4];
#pragma unroll
    for (int r = 0; r < 4; ++r) Iv[r] = 1.0f / Ssum[r];

    // ---------------- pass B: recompute, normalize, write attn, PV ----------
    f32x4 oacc[4] = {{0.f, 0.f, 0.f, 0.f}};

    for (int k0 = 0; k0 < S; k0 += 64) {
        __syncthreads();
        *(ush8*)&Ks[(t >> 3) * 72 + (t & 7) * 8] =
            *(const ush8*)(Kb + ((size_t)bh * S + k0 + (t >> 3)) * HD + (t & 7) * 8);
        {   // transposed V staging: conflict-free scalar writes
            ush8 v0 = *(const ush8*)(Vb + ((size_t)bh * S + k0 + lane) * HD + w * 8);
#pragma unroll
            for (int j = 0; j < 8; ++j)
                Vts[(w * 8 + j) * 72 + lane] = ((const u16*)&v0)[j];
        }
        __syncthreads();

        f32x4 c4[4];
#pragma unroll
        for (int ni = 0; ni < 4; ++ni) {
            bf16x8 kf0 = *(const bf16x8*)&Ks[(ni * 16 + lr) * 72 + lg * 8];
            bf16x8 kf1 = *(const bf16x8*)&Ks[(ni * 16 + lr) * 72 + 32 + lg * 8];
            f32x4 c = {0.f, 0.f, 0.f, 0.f};
            c = __builtin_amdgcn_mfma_f32_16x16x32_bf16(qa0, kf0, c, 0, 0, 0);
            c = __builtin_amdgcn_mfma_f32_16x16x32_bf16(qa1, kf1, c, 0, 0, 0);
            c4[ni] = c;
        }

        float idk[4]; int mk[4];
#pragma unroll
        for (int ni = 0; ni < 4; ++ni) {
            int k = k0 + ni * 16 + lr;
            idk[ni] = idf[b * S + k];
            mk[ni]  = amask[b * S + k];
        }
#pragma unroll
        for (int r = 0; r < 4; ++r) {
            const int q = q0 + w * 16 + lg * 4 + r;
            const int* drow = dist + ((size_t)b * S + q) * S + k0;
            float* arow = attn + ((size_t)bh * S + q) * S + k0;
#pragma unroll
            for (int ni = 0; ni < 4; ++ni) {
                int dc = drow[ni * 16 + lr];
                dc = dc < 0 ? 0 : (dc > 50 ? 50 : dc);
                float sv = c4[ni][r] * 0.125f + SeH[dc] + rwv * (idqv[r] + idk[ni]);
                if (mk[ni] == 0) sv = -INFINITY;
                float p = __expf(sv - M[r]) * Iv[r];
                arow[ni * 16 + lr] = p;
                QPs[(w * 16 + lg * 4 + r) * 72 + ni * 16 + lr] = f2bf(p);
            }
        }
        // PV: wave-local P (same wave wrote these rows; LDS ops in-order)
        bf16x8 pa0 = *(const bf16x8*)&QPs[(w * 16 + lr) * 72 + lg * 8];
        bf16x8 pa1 = *(const bf16x8*)&QPs[(w * 16 + lr) * 72 + 32 + lg * 8];
#pragma unroll
        for (int ni = 0; ni < 4; ++ni) {
            bf16x8 vb0 = *(const bf16x8*)&Vts[(ni * 16 + lr) * 72 + lg * 8];
            bf16x8 vb1 = *(const bf16x8*)&Vts[(ni * 16 + lr) * 72 + 32 + lg * 8];
            oacc[ni] = __builtin_amdgcn_mfma_f32_16x16x32_bf16(pa0, vb0, oacc[ni], 0, 0, 0);
            oacc[ni] = __builtin_amdgcn_mfma_f32_16x16x32_bf16(pa1, vb1, oacc[ni], 0, 0, 0);
        }
    }

    // OH epilogue: split hi/lo bf16 for the out-projection GEMM
#pragma unroll
    for (int r = 0; r < 4; ++r) {
        const int q = q0 + w * 16 + lg * 4 + r;
#pragma unroll
        for (int ni = 0; ni < 4; ++ni) {
            float v = oacc[ni][r];
            u16 hi = f2bf(v);
            u16 lo = f2bf(v - bf2f(hi));
            size_t off = ((size_t)b * S + q) * HID + h * HD + ni * 16 + lr;
            OHh[off] = hi;
            OHl[off] = lo;
        }
    }
}

// ---------------------------------------------------------------------------
extern "C" void kernel_launch(void* const* d_in, const int* in_sizes, int n_in,
                              void* d_out, int out_size, void* d_ws, size_t ws_size,
                              hipStream_t stream)
{
    const float* hs   = (const float*)d_in[0];
    const int*   dist = (const int*)d_in[1];
    const float* idf  = (const float*)d_in[2];
    const int*   am   = (const int*)d_in[3];
    const float* Wq   = (const float*)d_in[4];
    const float* bq   = (const float*)d_in[5];
    const float* Wk   = (const float*)d_in[6];
    const float* bk   = (const float*)d_in[7];
    const float* Wv   = (const float*)d_in[8];
    const float* bv   = (const float*)d_in[9];
    const float* Wo   = (const float*)d_in[10];
    const float* bo   = (const float*)d_in[11];
    const float* se   = (const float*)d_in[12];
    const float* rw   = (const float*)d_in[13];

    float* out  = (float*)d_out;
    float* attn = out + (size_t)2 * S * HID;

    // X hi/lo hide in the (not yet written) attn output region
    u16* Xh = (u16*)attn;
    u16* Xl = Xh + (size_t)4096 * 1024;

    // workspace layout
    u16* Qb  = (u16*)d_ws;
    u16* Kb  = Qb  + (size_t)BH * S * HD;
    u16* Vb  = Kb  + (size_t)BH * S * HD;
    u16* OHh = Vb  + (size_t)BH * S * HD;
    u16* OHl = OHh + (size_t)4096 * 1024;
    u16* Woh = OHl + (size_t)4096 * 1024;
    u16* Wol = Woh + (size_t)1024 * 1024;
    u16* Wqh = Wol + (size_t)1024 * 1024;
    u16* Wql = Wqh + (size_t)1024 * 1024;
    u16* Wkh = Wql + (size_t)1024 * 1024;
    u16* Wkl = Wkh + (size_t)1024 * 1024;
    u16* Wvh = Wkl + (size_t)1024 * 1024;
    u16* Wvl = Wvh + (size_t)1024 * 1024;

    dim3 blk(256);
    split_all<<<dim3(8192), blk, 0, stream>>>(hs, Wq, Wk, Wv, Wo,
                                              Xh, Xl, Wqh, Wql, Wkh, Wkl,
                                              Wvh, Wvl, Woh, Wol);
    qkv_mfma<<<dim3(8, 32, 3), blk, 0, stream>>>(Xh, Xl, Wqh, Wql, Wkh, Wkl,
                                                 Wvh, Wvl, bq, bk, bv, Qb, Kb, Vb);
    attn_pv<<<dim3(512), dim3(512), 0, stream>>>(Qb, Kb, Vb, dist, idf, am, se, rw,
                                                 attn, OHh, OHl);
    out_mfma<<<dim3(8, 32), blk, 0, stream>>>(OHh, OHl, Woh, Wol, bo, out);
}